// Round 6
// baseline (89.762 us; speedup 1.0000x reference)
//
#include <hip/hip_runtime.h>
#include <hip/hip_bf16.h>

// B=2, D=512, N=2048, H=8, head=64.

using bf16x8 = __attribute__((ext_vector_type(8))) __bf16;
using f32x4  = __attribute__((ext_vector_type(4))) float;
using f32x16 = __attribute__((ext_vector_type(16))) float;
using us8    = __attribute__((ext_vector_type(8))) unsigned short;
using u32x4  = __attribute__((ext_vector_type(4))) unsigned int;

__device__ __forceinline__ unsigned short f2b(float f) {
  unsigned int u = __builtin_bit_cast(unsigned int, f);
  u += 0x7fffu + ((u >> 16) & 1u);
  return (unsigned short)(u >> 16);
}
__device__ __forceinline__ float b2f(unsigned short s) {
  unsigned int u = ((unsigned int)s) << 16;
  return __builtin_bit_cast(float, u);
}
__device__ __forceinline__ unsigned int cvtpk(float lo, float hi) {
  unsigned int w;
  asm("v_cvt_pk_bf16_f32 %0, %1, %2" : "=v"(w) : "v"(lo), "v"(hi));
  return w;
}
__device__ __forceinline__ void gl_lds16(const void* g, void* l) {
  __builtin_amdgcn_global_load_lds((const __attribute__((address_space(1))) void*)g,
                                   (__attribute__((address_space(3))) void*)l, 16, 0, 0);
}

// ------- fused pre-pass: feats transpose (f32->bf16) + weight permute + mask bias -------
__global__ __launch_bounds__(256) void k_pre(
    const float* __restrict__ fq, const float* __restrict__ fk,
    const float* __restrict__ Wq, const float* __restrict__ Wk,
    const float* __restrict__ Wf, const float* __restrict__ Wm,
    const int* __restrict__ mask,
    unsigned short* __restrict__ xqt, unsigned short* __restrict__ xkt,
    unsigned short* __restrict__ wqb, unsigned short* __restrict__ wkb,
    unsigned short* __restrict__ wfb, unsigned short* __restrict__ wmb,
    float* __restrict__ biasf)
{
  const int id = blockIdx.x;
  const int t = threadIdx.x;
  __shared__ float tile[64][65];

  if (id < 1024) {
    const int which = id >> 9;
    const int b = (id >> 8) & 1;
    const int i0 = ((id >> 5) & 7) * 64;
    const int n0 = (id & 31) * 64;
    const float* __restrict__ src = which ? fk : fq;
    unsigned short* __restrict__ dst = which ? xkt : xqt;
    const int cl = t & 63, rw = t >> 6;
    #pragma unroll
    for (int rr = 0; rr < 16; ++rr) {
      int il = rr * 4 + rw;
      tile[il][cl] = src[((size_t)b * 512 + i0 + il) * 2048 + n0 + cl];
    }
    __syncthreads();
    const int ci = (t & 31) * 2, rhalf = t >> 5;
    #pragma unroll
    for (int rr = 0; rr < 8; ++rr) {
      int nl = rr * 8 + rhalf;
      unsigned int v = (unsigned int)f2b(tile[ci][nl]) |
                       ((unsigned int)f2b(tile[ci + 1][nl]) << 16);
      *(unsigned int*)&dst[((size_t)b * 2048 + n0 + nl) * 512 + i0 + ci] = v;
    }
  } else if (id < 3072) {
    const int r = id - 1024;
    const int mat = r >> 9, cp = r & 511;
    if (mat < 3) {
      const float* W = (mat == 0) ? Wq : (mat == 1) ? Wk : Wf;
      unsigned short* O = (mat == 0) ? wqb : (mat == 1) ? wkb : wfb;
      const int orig = (cp & 63) * 8 + (cp >> 6);   // d*8+h
      for (int j = t; j < 512; j += 256)
        O[cp * 512 + j] = f2b(W[orig * 512 + j]);
    } else {
      for (int j = t; j < 512; j += 256) {
        int h = j >> 6, d = j & 63;
        wmb[cp * 512 + j] = f2b(Wm[cp * 512 + d * 8 + h]);
      }
    }
  } else {
    const int r = id - 3072;
    if (r < 16) {
      int i = r * 256 + t;
      biasf[i] = mask[i] ? 0.f : -100000.f;
    }
  }
}

// ---------------- QKV projections: 128x128 NT, gl_lds 2-phase double-buffer ----------------
__global__ __launch_bounds__(256) void k_proj(
    const unsigned short* __restrict__ xqt, const unsigned short* __restrict__ xkt,
    const unsigned short* __restrict__ wqp, const unsigned short* __restrict__ wkp,
    const unsigned short* __restrict__ wfp,
    const float* __restrict__ bq, const float* __restrict__ bk, const float* __restrict__ bfv,
    unsigned short* __restrict__ Qb, unsigned short* __restrict__ Kb, unsigned short* __restrict__ VTb)
{
  const int lid = blockIdx.x;                     // 0..383
  const int orig = (lid & 7) * 48 + (lid >> 3);   // bijective (384 = 8*48)
  const int z = orig >> 6;
  const int bid = orig & 63;
  const int b = z / 3, proj = z % 3;
  const int t = threadIdx.x, w = t >> 6, l = t & 63, q = l >> 4, m16 = l & 15;
  const int wm = w >> 1, wn = w & 1;

  __shared__ __attribute__((aligned(16))) unsigned short As[2][8192];
  __shared__ __attribute__((aligned(16))) unsigned short Bs[2][8192];

  const unsigned short* A;
  const unsigned short* Bt;
  int mt, nt_;
  if (proj < 2) {
    mt = bid >> 2; nt_ = bid & 3;
    A  = (proj == 0 ? xqt : xkt) + (size_t)b * 2048 * 512 + (size_t)mt * 128 * 512;
    Bt = (proj == 0 ? wqp : wkp) + (size_t)nt_ * 128 * 512;
  } else {
    mt = bid & 3; nt_ = bid >> 2;
    A  = wfp + (size_t)mt * 128 * 512;
    Bt = xkt + (size_t)b * 2048 * 512 + (size_t)nt_ * 128 * 512;
  }

  f32x4 acc[4][4];
  const f32x4 fz = {0.f, 0.f, 0.f, 0.f};
  #pragma unroll
  for (int mf = 0; mf < 4; ++mf)
    #pragma unroll
    for (int nf = 0; nf < 4; ++nf) acc[mf][nf] = fz;

#define PROJ_STAGE(BUF, KS)                                                          \
  {                                                                                  \
    _Pragma("unroll")                                                                \
    for (int c = 0; c < 4; ++c) {                                                    \
      int slot = c * 256 + t;                                                        \
      int row = slot >> 3, j = slot & 7;                                             \
      int jj = j ^ (row & 7);                                                        \
      gl_lds16(A  + (size_t)row * 512 + (KS) * 64 + jj * 8,                          \
               (char*)As[BUF] + (c * 256 + w * 64) * 16);                            \
      gl_lds16(Bt + (size_t)row * 512 + (KS) * 64 + jj * 8,                          \
               (char*)Bs[BUF] + (c * 256 + w * 64) * 16);                            \
    }                                                                                \
  }

  PROJ_STAGE(0, 0)
  asm volatile("s_waitcnt vmcnt(0)" ::: "memory");
  __syncthreads();

  for (int ks = 0; ks < 8; ++ks) {
    const int cur = ks & 1;
    if (ks < 7) PROJ_STAGE(cur ^ 1, ks + 1)
    #pragma unroll
    for (int kk = 0; kk < 2; ++kk) {
      bf16x8 av[4], bv[4];
      #pragma unroll
      for (int mf = 0; mf < 4; ++mf) {
        int row = wm * 64 + mf * 16 + m16;
        av[mf] = *(const bf16x8*)&As[cur][row * 64 + (((kk * 4 + q) ^ (row & 7)) << 3)];
      }
      #pragma unroll
      for (int nf = 0; nf < 4; ++nf) {
        int row = wn * 64 + nf * 16 + m16;
        bv[nf] = *(const bf16x8*)&Bs[cur][row * 64 + (((kk * 4 + q) ^ (row & 7)) << 3)];
      }
      #pragma unroll
      for (int mf = 0; mf < 4; ++mf)
        #pragma unroll
        for (int nf = 0; nf < 4; ++nf)
          acc[mf][nf] = __builtin_amdgcn_mfma_f32_16x16x32_bf16(av[mf], bv[nf], acc[mf][nf], 0, 0, 0);
    }
    if (ks < 7) {
      asm volatile("s_waitcnt vmcnt(0)" ::: "memory");
      __syncthreads();
    }
  }
#undef PROJ_STAGE

  const float QSCALE = 0.18033688011112042f;   // log2(e)/8 folded into Q

  if (proj < 2) {
    const float* bias = (proj == 0) ? bq : bk;
    unsigned short* dst = (proj == 0) ? Qb : Kb;
    #pragma unroll
    for (int mf = 0; mf < 4; ++mf)
      #pragma unroll
      for (int nf = 0; nf < 4; ++nf)
        #pragma unroll
        for (int r = 0; r < 4; ++r) {
          int n  = mt * 128 + wm * 64 + mf * 16 + q * 4 + r;
          int cp = nt_ * 128 + wn * 64 + nf * 16 + m16;
          int h = cp >> 6, d = cp & 63;
          float v = acc[mf][nf][r] + bias[d * 8 + h];
          if (proj == 0) v *= QSCALE;
          dst[((size_t)(b * 8 + h) * 2048 + n) * 64 + d] = f2b(v);
        }
  } else {
    #pragma unroll
    for (int mf = 0; mf < 4; ++mf)
      #pragma unroll
      for (int nf = 0; nf < 4; ++nf)
        #pragma unroll
        for (int r = 0; r < 4; ++r) {
          int cp = mt * 128 + wm * 64 + mf * 16 + q * 4 + r;
          int n  = nt_ * 128 + wn * 64 + nf * 16 + m16;
          int h = cp >> 6, d = cp & 63;
          float v = acc[mf][nf][r] + bfv[d * 8 + h];
          VTb[((size_t)(b * 8 + h) * 64 + d) * 2048 + n] = f2b(v);
        }
  }
}

// -------- flash attention v3: QBLK=128, q-split waves, shared KV staging (KVBLK=64) --------
// 256 blocks (XCD-swizzled: 2 bh per XCD -> KV L2-resident, traffic halved vs QBLK=64).
// Wave w owns q-rows [nt*128 + w*32, +32); KV chunks staged once per block, 2-phase dbuf.
__global__ __launch_bounds__(256) void k_attn3(
    const unsigned short* __restrict__ Qb, const unsigned short* __restrict__ Kb,
    const unsigned short* __restrict__ VTb, const float* __restrict__ biasf,
    unsigned short* __restrict__ OT)
{
  const int lid = blockIdx.x;                       // 0..255
  const int orig = (lid & 7) * 32 + (lid >> 3);     // bijective (256 = 8*32)
  const int bh = orig >> 4, b = bh >> 3, h = bh & 7;
  const int nt = orig & 15;                         // q-tile of 128
  const int t = threadIdx.x, w = t >> 6, l = t & 63;
  const int q31 = l & 31, hi = l >> 5;

  // shared KV double-buffer: K[2][64][64] + V[2][64][64] bf16 = 32 KB
  __shared__ __attribute__((aligned(16))) char lds_all[32768];
  char* kb0 = lds_all;            // K buffers at 0, 8192
  char* vb0 = lds_all + 16384;    // V buffers at 16384, 24576

  const unsigned short* Kp = Kb + (size_t)bh * (2048 * 64);
  const unsigned short* Vp = VTb + (size_t)bh * (64 * 2048);
  const float* brow = biasf + b * 2048;
  const int qbase = nt * 128 + w * 32;

  // Q fragments (B-operand): lane holds Q[qbase+q31][tq*16+hi*8+j]
  bf16x8 qfr[4];
  {
    const unsigned short* Qp = Qb + ((size_t)bh * 2048 + qbase) * 64;
    #pragma unroll
    for (int tq = 0; tq < 4; ++tq)
      qfr[tq] = *(const bf16x8*)&Qp[q31 * 64 + tq * 16 + hi * 8];
  }

  f32x16 z16;
  #pragma unroll
  for (int r = 0; r < 16; ++r) z16[r] = 0.f;
  f32x16 oacc[2];       // [df] : O^T[d=df*32+crow][q=q31]
  oacc[0] = z16; oacc[1] = z16;
  float lpart = 0.f;

  const int srow = t >> 3, sslot = t & 7;   // staging: row = c*32+srow, slot = sslot

  // STAGE(buf, kv0): cooperative, 4 gl_lds per thread, rule-21 pre-swizzled source
#define ATTN_STAGE(BUF, KV0)                                                          \
  {                                                                                   \
    _Pragma("unroll")                                                                 \
    for (int c = 0; c < 2; ++c) {                                                     \
      int row = c * 32 + srow;                                                        \
      gl_lds16(Kp + (size_t)((KV0) + row) * 64 + (sslot ^ (row & 7)) * 8,             \
               kb0 + (BUF) * 8192 + c * 4096 + w * 1024);                             \
      gl_lds16(Vp + (size_t)row * 2048 + (KV0) + (sslot ^ (row & 7)) * 8,             \
               vb0 + (BUF) * 8192 + c * 4096 + w * 1024);                             \
    }                                                                                 \
  }

  ATTN_STAGE(0, 0)
  asm volatile("s_waitcnt vmcnt(0)" ::: "memory");
  __syncthreads();

  for (int i = 0; i < 32; ++i) {
    const int cur = i & 1;
    const int kv0 = i * 64;

    if (i < 31) ATTN_STAGE(cur ^ 1, kv0 + 64)

    const char* kb = kb0 + cur * 8192;
    const char* vb = vb0 + cur * 8192;

    // mask bias for this chunk (L1/L2-hot; waits folded into vmcnt below)
    float4 bias[2][4];
    #pragma unroll
    for (int ks = 0; ks < 2; ++ks)
      #pragma unroll
      for (int g = 0; g < 4; ++g)
        bias[ks][g] = *(const float4*)&brow[kv0 + ks * 32 + g * 8 + hi * 4];

    #pragma unroll
    for (int ks = 0; ks < 2; ++ks) {     // two 32-row kv subtiles
      // K fragments (A-operand): K[ks*32+q31][tq*16+hi*8+j]
      bf16x8 ak[4];
      #pragma unroll
      for (int tq = 0; tq < 4; ++tq)
        ak[tq] = *(const bf16x8*)(kb + (ks * 32 + q31) * 128 + ((((tq << 1) | hi) ^ (q31 & 7)) * 16));

      f32x16 sacc;
      __builtin_amdgcn_s_setprio(1);
      sacc = __builtin_amdgcn_mfma_f32_32x32x16_bf16(ak[0], qfr[0], z16, 0, 0, 0);
      #pragma unroll
      for (int tq = 1; tq < 4; ++tq)
        sacc = __builtin_amdgcn_mfma_f32_32x32x16_bf16(ak[tq], qfr[tq], sacc, 0, 0, 0);
      __builtin_amdgcn_s_setprio(0);

      // e = exp2(s + maskbias); kv-rel row of reg r = (r&3) + 8*(r>>2) + 4*hi
      float e[16];
      #pragma unroll
      for (int g = 0; g < 4; ++g) {
        e[g*4+0] = __builtin_amdgcn_exp2f(sacc[g*4+0] + bias[ks][g].x);
        e[g*4+1] = __builtin_amdgcn_exp2f(sacc[g*4+1] + bias[ks][g].y);
        e[g*4+2] = __builtin_amdgcn_exp2f(sacc[g*4+2] + bias[ks][g].z);
        e[g*4+3] = __builtin_amdgcn_exp2f(sacc[g*4+3] + bias[ks][g].w);
      }
      // tree sum (depth 4)
      {
        float s0 = e[0]+e[1], s1 = e[2]+e[3], s2 = e[4]+e[5], s3 = e[6]+e[7];
        float s4 = e[8]+e[9], s5 = e[10]+e[11], s6 = e[12]+e[13], s7 = e[14]+e[15];
        float t0 = s0+s1, t1 = s2+s3, t2 = s4+s5, t3 = s6+s7;
        lpart += (t0+t1) + (t2+t3);
      }

      // pack + permlane32_swap: PV B-operand in registers (T12)
      unsigned int W[8];
      #pragma unroll
      for (int j = 0; j < 8; ++j) W[j] = cvtpk(e[2*j], e[2*j+1]);
      asm("v_permlane32_swap_b32 %0, %1" : "+v"(W[0]), "+v"(W[2]));
      asm("v_permlane32_swap_b32 %0, %1" : "+v"(W[1]), "+v"(W[3]));
      asm("v_permlane32_swap_b32 %0, %1" : "+v"(W[4]), "+v"(W[6]));
      asm("v_permlane32_swap_b32 %0, %1" : "+v"(W[5]), "+v"(W[7]));
      u32x4 lo4 = {W[0], W[1], W[2], W[3]};
      u32x4 hi4 = {W[4], W[5], W[6], W[7]};
      bf16x8 pb0 = __builtin_bit_cast(bf16x8, lo4);
      bf16x8 pb1 = __builtin_bit_cast(bf16x8, hi4);

      // V fragments (A-operand): V^T[df*32+q31][(ks*2+tt)*16+hi*8+j]
      bf16x8 av00 = *(const bf16x8*)(vb + q31 * 128 + (((((ks*2+0) << 1) | hi) ^ (q31 & 7)) * 16));
      bf16x8 av01 = *(const bf16x8*)(vb + q31 * 128 + (((((ks*2+1) << 1) | hi) ^ (q31 & 7)) * 16));
      bf16x8 av10 = *(const bf16x8*)(vb + (32 + q31) * 128 + (((((ks*2+0) << 1) | hi) ^ (q31 & 7)) * 16));
      bf16x8 av11 = *(const bf16x8*)(vb + (32 + q31) * 128 + (((((ks*2+1) << 1) | hi) ^ (q31 & 7)) * 16));

      __builtin_amdgcn_s_setprio(1);
      oacc[0] = __builtin_amdgcn_mfma_f32_32x32x16_bf16(av00, pb0, oacc[0], 0, 0, 0);
      oacc[0] = __builtin_amdgcn_mfma_f32_32x32x16_bf16(av01, pb1, oacc[0], 0, 0, 0);
      oacc[1] = __builtin_amdgcn_mfma_f32_32x32x16_bf16(av10, pb0, oacc[1], 0, 0, 0);
      oacc[1] = __builtin_amdgcn_mfma_f32_32x32x16_bf16(av11, pb1, oacc[1], 0, 0, 0);
      __builtin_amdgcn_s_setprio(0);
    }

    asm volatile("s_waitcnt vmcnt(0)" ::: "memory");
    __syncthreads();
  }
#undef ATTN_STAGE

  // epilogue: normalize, transpose via wave-private LDS (4KB each), coalesced store
  unsigned short* ot = (unsigned short*)(lds_all + w * 4096);   // [32 q][64 d] swizzled
  {
    float ls = lpart + __shfl_xor(lpart, 32);
    float rinv = __builtin_amdgcn_rcpf(ls);
    #pragma unroll
    for (int df = 0; df < 2; ++df)
      #pragma unroll
      for (int rg = 0; rg < 4; ++rg)
        #pragma unroll
        for (int pr = 0; pr < 2; ++pr) {
          int r0 = rg * 4 + pr * 2;
          unsigned int wv = cvtpk(oacc[df][r0] * rinv, oacc[df][r0 + 1] * rinv);
          *(unsigned int*)((char*)ot + q31 * 128 + (((df * 4 + rg) ^ (q31 & 7)) * 16) + hi * 8 + pr * 4) = wv;
        }
  }
  #pragma unroll
  for (int j = 0; j < 4; ++j) {
    int qq = j * 8 + (l >> 3);
    int sl = l & 7;
    us8 val = *(const us8*)((const char*)ot + qq * 128 + ((sl ^ (qq & 7)) * 16));
    *(us8*)&OT[((size_t)b * 2048 + qbase + qq) * 512 + h * 64 + sl * 8] = val;
  }
}

// --------- fused: final projection + bias + f32 residual + channel-LN + transposed store ---------
__global__ __launch_bounds__(256) void k_out(
    const unsigned short* __restrict__ OT, const unsigned short* __restrict__ wmw,
    const float* __restrict__ bm, const float* __restrict__ fq,
    const float* __restrict__ g, const float* __restrict__ be,
    float* __restrict__ out)
{
  const int b = blockIdx.y;
  const int n0 = blockIdx.x * 32;
  const int t = threadIdx.x, w = t >> 6, l = t & 63, q = l >> 4, m16 = l & 15;

  __shared__ __attribute__((aligned(16))) unsigned short As[2][2048];    // 2 x 4 KB
  __shared__ __attribute__((aligned(16))) unsigned short Bs[2][32768];   // 2 x 64 KB
  __shared__ float ssum[4][32], ssq[4][32];

  f32x4 acc[2][8];
  const f32x4 fz = {0.f, 0.f, 0.f, 0.f};
  #pragma unroll
  for (int mf = 0; mf < 2; ++mf)
    #pragma unroll
    for (int nf = 0; nf < 8; ++nf) acc[mf][nf] = fz;

  const unsigned short* Abase = OT + ((size_t)b * 2048 + n0) * 512;
  const unsigned short* Bbase = wmw;

#define OUT_STAGE(BUF, KS)                                                          \
  {                                                                                 \
    { int row = t >> 3, j = t & 7;                                                  \
      gl_lds16(Abase + (size_t)row * 512 + (KS) * 64 + ((j ^ (row & 7)) * 8),       \
               (char*)As[BUF] + w * 1024); }                                        \
    _Pragma("unroll")                                                               \
    for (int c = 0; c < 16; ++c) {                                                  \
      int slot = c * 256 + t;                                                       \
      int row = slot >> 3, j = slot & 7;                                            \
      gl_lds16(Bbase + (size_t)row * 512 + (KS) * 64 + ((j ^ (row & 7)) * 8),       \
               (char*)Bs[BUF] + (c * 256 + w * 64) * 16);                           \
    }                                                                               \
  }

  OUT_STAGE(0, 0)
  asm volatile("s_waitcnt vmcnt(0)" ::: "memory");
  __syncthreads();

  for (int ks = 0; ks < 8; ++ks) {
    const int cur = ks & 1;
    if (ks < 7) OUT_STAGE(cur ^ 1, ks + 1)
    #pragma unroll
    for (int kk = 0; kk < 2; ++kk) {
      bf16x8 av[2];
      #pragma unroll
      for (int mf = 0; mf < 2; ++mf) {
        int row = mf * 16 + m16;
        av[mf] = *(const bf16x8*)((const char*)As[cur] + row * 128 + (((kk * 4 + q) ^ (row & 7)) * 16));
      }
      #pragma unroll
      for (int nf = 0; nf < 8; ++nf) {
        int row = w * 128 + nf * 16 + m16;
        bf16x8 bv = *(const bf16x8*)((const char*)Bs[cur] + row * 128 + (((kk * 4 + q) ^ (row & 7)) * 16));
        acc[0][nf] = __builtin_amdgcn_mfma_f32_16x16x32_bf16(av[0], bv, acc[0][nf], 0, 0, 0);
        acc[1][nf] = __builtin_amdgcn_mfma_f32_16x16x32_bf16(av[1], bv, acc[1][nf], 0, 0, 0);
      }
    }
    if (ks < 7) {
      asm volatile("s_waitcnt vmcnt(0)" ::: "memory");
      __syncthreads();
    }
  }
#undef OUT_STAGE

  float gv[8], bev[8], bmv[8];
  #pragma unroll
  for (int nf = 0; nf < 8; ++nf) {
    int c = w * 128 + nf * 16 + m16;
    gv[nf] = g[c]; bev[nf] = be[c]; bmv[nf] = bm[c];
  }
  #pragma unroll
  for (int mf = 0; mf < 2; ++mf)
    #pragma unroll
    for (int nf = 0; nf < 8; ++nf) {
      int c = w * 128 + nf * 16 + m16;
      f32x4 res = *(const f32x4*)&fq[((size_t)b * 512 + c) * 2048 + n0 + mf * 16 + q * 4];
      #pragma unroll
      for (int r = 0; r < 4; ++r)
        acc[mf][nf][r] += bmv[nf] + res[r];
    }
  #pragma unroll
  for (int mf = 0; mf < 2; ++mf)
    #pragma unroll
    for (int r = 0; r < 4; ++r) {
      float ps = 0.f, pss = 0.f;
      #pragma unroll
      for (int nf = 0; nf < 8; ++nf) {
        float v = acc[mf][nf][r];
        ps += v; pss += v * v;
      }
      ps += __shfl_xor(ps, 1); pss += __shfl_xor(pss, 1);
      ps += __shfl_xor(ps, 2); pss += __shfl_xor(pss, 2);
      ps += __shfl_xor(ps, 4); pss += __shfl_xor(pss, 4);
      ps += __shfl_xor(ps, 8); pss += __shfl_xor(pss, 8);
      if (m16 == 0) {
        ssum[w][mf * 16 + q * 4 + r] = ps;
        ssq[w][mf * 16 + q * 4 + r] = pss;
      }
    }
  __syncthreads();
  #pragma unroll
  for (int mf = 0; mf < 2; ++mf)
    #pragma unroll
    for (int r = 0; r < 4; ++r) {
      int nl = mf * 16 + q * 4 + r;
      float S  = ssum[0][nl] + ssum[1][nl] + ssum[2][nl] + ssum[3][nl];
      float SS = ssq[0][nl] + ssq[1][nl] + ssq[2][nl] + ssq[3][nl];
      float mu = S * (1.f / 512.f);
      float var = SS * (1.f / 512.f) - mu * mu;
      float rstd = rsqrtf(var + 1e-5f);
      #pragma unroll
      for (int nf = 0; nf < 8; ++nf)
        acc[mf][nf][r] = (acc[mf][nf][r] - mu) * rstd * gv[nf] + bev[nf];
    }
  #pragma unroll
  for (int mf = 0; mf < 2; ++mf)
    #pragma unroll
    for (int nf = 0; nf < 8; ++nf) {
      int c = w * 128 + nf * 16 + m16;
      *(f32x4*)&out[((size_t)b * 512 + c) * 2048 + n0 + mf * 16 + q * 4] = acc[mf][nf];
    }
}

// ---------------- launcher ----------------
extern "C" void kernel_launch(void* const* d_in, const int* in_sizes, int n_in,
                              void* d_out, int out_size, void* d_ws, size_t ws_size,
                              hipStream_t stream) {
  const float* fq  = (const float*)d_in[0];
  const float* fk  = (const float*)d_in[1];
  const int*   msk = (const int*)d_in[2];
  const float* Wq  = (const float*)d_in[3];
  const float* bq  = (const float*)d_in[4];
  const float* Wk  = (const float*)d_in[5];
  const float* bk  = (const float*)d_in[6];
  const float* Wf  = (const float*)d_in[7];
  const float* bfv = (const float*)d_in[8];
  const float* Wm  = (const float*)d_in[9];
  const float* bm  = (const float*)d_in[10];
  const float* lng = (const float*)d_in[11];
  const float* lnb = (const float*)d_in[12];
  float* out = (float*)d_out;

  char* ws = (char*)d_ws;
  const size_t MB = 1024 * 1024;
  unsigned short* xqt = (unsigned short*)(ws + 0 * MB);        // 4 MB  [b][n][512] bf16
  unsigned short* xkt = (unsigned short*)(ws + 4 * MB);        // 4 MB
  unsigned short* wqb = (unsigned short*)(ws + 8 * MB);        // 512 KB
  unsigned short* wkb = (unsigned short*)(ws + 8 * MB + 512 * 1024);
  unsigned short* wfb = (unsigned short*)(ws + 9 * MB);
  unsigned short* wmb = (unsigned short*)(ws + 9 * MB + 512 * 1024);
  unsigned short* Qb  = (unsigned short*)(ws + 10 * MB);       // 4 MB  [bh][n][64]
  unsigned short* Kb  = (unsigned short*)(ws + 14 * MB);       // 4 MB  [bh][m][64]
  unsigned short* VTb = (unsigned short*)(ws + 18 * MB);       // 4 MB  [bh][64][m]
  unsigned short* OTb = (unsigned short*)(ws + 22 * MB);       // 4 MB  [b][n][512]
  float*          biasf = (float*)(ws + 26 * MB);              // 16 KB

  hipLaunchKernelGGL(k_pre, dim3(3088), dim3(256), 0, stream,
                     fq, fk, Wq, Wk, Wf, Wm, msk, xqt, xkt, wqb, wkb, wfb, wmb, biasf);
  hipLaunchKernelGGL(k_proj, dim3(384), dim3(256), 0, stream,
                     xqt, xkt, wqb, wkb, wfb, bq, bk, bfv, Qb, Kb, VTb);
  hipLaunchKernelGGL(k_attn3, dim3(256), dim3(256), 0, stream, Qb, Kb, VTb, biasf, OTb);
  hipLaunchKernelGGL(k_out, dim3(64, 2), dim3(256), 0, stream,
                     OTb, wmb, bm, fq, lng, lnb, out);
}

// Round 7
// 83.914 us; speedup vs baseline: 1.0697x; 1.0697x over previous
//
#include <hip/hip_runtime.h>
#include <hip/hip_bf16.h>

// B=2, D=512, N=2048, H=8, head=64.

using bf16x8 = __attribute__((ext_vector_type(8))) __bf16;
using f32x4  = __attribute__((ext_vector_type(4))) float;
using f32x16 = __attribute__((ext_vector_type(16))) float;
using us8    = __attribute__((ext_vector_type(8))) unsigned short;
using u32x4  = __attribute__((ext_vector_type(4))) unsigned int;

__device__ __forceinline__ unsigned short f2b(float f) {
  unsigned int u = __builtin_bit_cast(unsigned int, f);
  u += 0x7fffu + ((u >> 16) & 1u);
  return (unsigned short)(u >> 16);
}
__device__ __forceinline__ float b2f(unsigned short s) {
  unsigned int u = ((unsigned int)s) << 16;
  return __builtin_bit_cast(float, u);
}
__device__ __forceinline__ unsigned int cvtpk(float lo, float hi) {
  unsigned int w;
  asm("v_cvt_pk_bf16_f32 %0, %1, %2" : "=v"(w) : "v"(lo), "v"(hi));
  return w;
}
__device__ __forceinline__ void gl_lds16(const void* g, void* l) {
  __builtin_amdgcn_global_load_lds((const __attribute__((address_space(1))) void*)g,
                                   (__attribute__((address_space(3))) void*)l, 16, 0, 0);
}

// ------- fused pre-pass: feats transpose (f32->bf16) + weight permute + mask bias -------
__global__ __launch_bounds__(256) void k_pre(
    const float* __restrict__ fq, const float* __restrict__ fk,
    const float* __restrict__ Wq, const float* __restrict__ Wk,
    const float* __restrict__ Wf, const float* __restrict__ Wm,
    const int* __restrict__ mask,
    unsigned short* __restrict__ xqt, unsigned short* __restrict__ xkt,
    unsigned short* __restrict__ wqb, unsigned short* __restrict__ wkb,
    unsigned short* __restrict__ wfb, unsigned short* __restrict__ wmb,
    float* __restrict__ biasf)
{
  const int id = blockIdx.x;
  const int t = threadIdx.x;
  __shared__ float tile[64][65];

  if (id < 1024) {
    const int which = id >> 9;
    const int b = (id >> 8) & 1;
    const int i0 = ((id >> 5) & 7) * 64;
    const int n0 = (id & 31) * 64;
    const float* __restrict__ src = which ? fk : fq;
    unsigned short* __restrict__ dst = which ? xkt : xqt;
    const int cl = t & 63, rw = t >> 6;
    #pragma unroll
    for (int rr = 0; rr < 16; ++rr) {
      int il = rr * 4 + rw;
      tile[il][cl] = src[((size_t)b * 512 + i0 + il) * 2048 + n0 + cl];
    }
    __syncthreads();
    const int ci = (t & 31) * 2, rhalf = t >> 5;
    #pragma unroll
    for (int rr = 0; rr < 8; ++rr) {
      int nl = rr * 8 + rhalf;
      unsigned int v = (unsigned int)f2b(tile[ci][nl]) |
                       ((unsigned int)f2b(tile[ci + 1][nl]) << 16);
      *(unsigned int*)&dst[((size_t)b * 2048 + n0 + nl) * 512 + i0 + ci] = v;
    }
  } else if (id < 3072) {
    const int r = id - 1024;
    const int mat = r >> 9, cp = r & 511;
    if (mat < 3) {
      const float* W = (mat == 0) ? Wq : (mat == 1) ? Wk : Wf;
      unsigned short* O = (mat == 0) ? wqb : (mat == 1) ? wkb : wfb;
      const int orig = (cp & 63) * 8 + (cp >> 6);   // d*8+h
      for (int j = t; j < 512; j += 256)
        O[cp * 512 + j] = f2b(W[orig * 512 + j]);
    } else {
      for (int j = t; j < 512; j += 256) {
        int h = j >> 6, d = j & 63;
        wmb[cp * 512 + j] = f2b(Wm[cp * 512 + d * 8 + h]);
      }
    }
  } else {
    const int r = id - 3072;
    if (r < 16) {
      int i = r * 256 + t;
      biasf[i] = mask[i] ? 0.f : -100000.f;
    }
  }
}

// ---------------- QKV projections: 128x128 NT, gl_lds 2-phase double-buffer ----------------
__global__ __launch_bounds__(256) void k_proj(
    const unsigned short* __restrict__ xqt, const unsigned short* __restrict__ xkt,
    const unsigned short* __restrict__ wqp, const unsigned short* __restrict__ wkp,
    const unsigned short* __restrict__ wfp,
    const float* __restrict__ bq, const float* __restrict__ bk, const float* __restrict__ bfv,
    unsigned short* __restrict__ Qb, unsigned short* __restrict__ Kb, unsigned short* __restrict__ VTb)
{
  const int lid = blockIdx.x;                     // 0..383
  const int orig = (lid & 7) * 48 + (lid >> 3);   // bijective (384 = 8*48)
  const int z = orig >> 6;
  const int bid = orig & 63;
  const int b = z / 3, proj = z % 3;
  const int t = threadIdx.x, w = t >> 6, l = t & 63, q = l >> 4, m16 = l & 15;
  const int wm = w >> 1, wn = w & 1;

  __shared__ __attribute__((aligned(16))) unsigned short As[2][8192];
  __shared__ __attribute__((aligned(16))) unsigned short Bs[2][8192];

  const unsigned short* A;
  const unsigned short* Bt;
  int mt, nt_;
  if (proj < 2) {
    mt = bid >> 2; nt_ = bid & 3;
    A  = (proj == 0 ? xqt : xkt) + (size_t)b * 2048 * 512 + (size_t)mt * 128 * 512;
    Bt = (proj == 0 ? wqp : wkp) + (size_t)nt_ * 128 * 512;
  } else {
    mt = bid & 3; nt_ = bid >> 2;
    A  = wfp + (size_t)mt * 128 * 512;
    Bt = xkt + (size_t)b * 2048 * 512 + (size_t)nt_ * 128 * 512;
  }

  f32x4 acc[4][4];
  const f32x4 fz = {0.f, 0.f, 0.f, 0.f};
  #pragma unroll
  for (int mf = 0; mf < 4; ++mf)
    #pragma unroll
    for (int nf = 0; nf < 4; ++nf) acc[mf][nf] = fz;

#define PROJ_STAGE(BUF, KS)                                                          \
  {                                                                                  \
    _Pragma("unroll")                                                                \
    for (int c = 0; c < 4; ++c) {                                                    \
      int slot = c * 256 + t;                                                        \
      int row = slot >> 3, j = slot & 7;                                             \
      int jj = j ^ (row & 7);                                                        \
      gl_lds16(A  + (size_t)row * 512 + (KS) * 64 + jj * 8,                          \
               (char*)As[BUF] + (c * 256 + w * 64) * 16);                            \
      gl_lds16(Bt + (size_t)row * 512 + (KS) * 64 + jj * 8,                          \
               (char*)Bs[BUF] + (c * 256 + w * 64) * 16);                            \
    }                                                                                \
  }

  PROJ_STAGE(0, 0)
  asm volatile("s_waitcnt vmcnt(0)" ::: "memory");
  __syncthreads();

  for (int ks = 0; ks < 8; ++ks) {
    const int cur = ks & 1;
    if (ks < 7) PROJ_STAGE(cur ^ 1, ks + 1)
    #pragma unroll
    for (int kk = 0; kk < 2; ++kk) {
      bf16x8 av[4], bv[4];
      #pragma unroll
      for (int mf = 0; mf < 4; ++mf) {
        int row = wm * 64 + mf * 16 + m16;
        av[mf] = *(const bf16x8*)&As[cur][row * 64 + (((kk * 4 + q) ^ (row & 7)) << 3)];
      }
      #pragma unroll
      for (int nf = 0; nf < 4; ++nf) {
        int row = wn * 64 + nf * 16 + m16;
        bv[nf] = *(const bf16x8*)&Bs[cur][row * 64 + (((kk * 4 + q) ^ (row & 7)) << 3)];
      }
      #pragma unroll
      for (int mf = 0; mf < 4; ++mf)
        #pragma unroll
        for (int nf = 0; nf < 4; ++nf)
          acc[mf][nf] = __builtin_amdgcn_mfma_f32_16x16x32_bf16(av[mf], bv[nf], acc[mf][nf], 0, 0, 0);
    }
    if (ks < 7) {
      asm volatile("s_waitcnt vmcnt(0)" ::: "memory");
      __syncthreads();
    }
  }
#undef PROJ_STAGE

  const float QSCALE = 0.18033688011112042f;   // log2(e)/8 folded into Q

  if (proj < 2) {
    const float* bias = (proj == 0) ? bq : bk;
    unsigned short* dst = (proj == 0) ? Qb : Kb;
    #pragma unroll
    for (int mf = 0; mf < 4; ++mf)
      #pragma unroll
      for (int nf = 0; nf < 4; ++nf)
        #pragma unroll
        for (int r = 0; r < 4; ++r) {
          int n  = mt * 128 + wm * 64 + mf * 16 + q * 4 + r;
          int cp = nt_ * 128 + wn * 64 + nf * 16 + m16;
          int h = cp >> 6, d = cp & 63;
          float v = acc[mf][nf][r] + bias[d * 8 + h];
          if (proj == 0) v *= QSCALE;
          dst[((size_t)(b * 8 + h) * 2048 + n) * 64 + d] = f2b(v);
        }
  } else {
    #pragma unroll
    for (int mf = 0; mf < 4; ++mf)
      #pragma unroll
      for (int nf = 0; nf < 4; ++nf)
        #pragma unroll
        for (int r = 0; r < 4; ++r) {
          int cp = mt * 128 + wm * 64 + mf * 16 + q * 4 + r;
          int n  = nt_ * 128 + wn * 64 + nf * 16 + m16;
          int h = cp >> 6, d = cp & 63;
          float v = acc[mf][nf][r] + bfv[d * 8 + h];
          VTb[((size_t)(b * 8 + h) * 64 + d) * 2048 + n] = f2b(v);
        }
  }
}

// ------- flash attention v4: wave-split KV, global->reg K/V (no LDS in main loop) -------
// 512 blocks (XCD-swizzled), 4 waves each own a disjoint KV quarter stream; no barriers
// in the main loop; register double-buffer gives depth-1 chunk prefetch; LDS only for
// the cross-wave combine epilogue (verified in R5).
__global__ __launch_bounds__(256, 2) void k_attn4(
    const unsigned short* __restrict__ Qb, const unsigned short* __restrict__ Kb,
    const unsigned short* __restrict__ VTb, const float* __restrict__ biasf,
    unsigned short* __restrict__ OT)
{
  const int lid = blockIdx.x;                       // 0..511
  const int orig = ((lid & 7) << 6) | (lid >> 3);   // bijective (512 = 8*64)
  const int bh = orig >> 5, b = bh >> 3, h = bh & 7;
  const int nt = orig & 31;
  const int t = threadIdx.x, w = t >> 6, l = t & 63;
  const int q31 = l & 31, hi = l >> 5;

  __shared__ __attribute__((aligned(16))) char lds_all[70656];  // combine only

  const unsigned short* Kp = Kb + (size_t)bh * (2048 * 64);
  const unsigned short* Vp = VTb + (size_t)bh * (64 * 2048);
  const float* brow = biasf + b * 2048;

  // Q fragments (B-operand): lane holds Q[qf*32+q31][tq*16+hi*8+j]
  bf16x8 qfr[2][4];
  {
    const unsigned short* Qp = Qb + ((size_t)bh * 2048 + nt * 64) * 64;
    #pragma unroll
    for (int qf = 0; qf < 2; ++qf)
      #pragma unroll
      for (int tq = 0; tq < 4; ++tq)
        qfr[qf][tq] = *(const bf16x8*)&Qp[(qf * 32 + q31) * 64 + tq * 16 + hi * 8];
  }

  f32x16 z16;
  #pragma unroll
  for (int r = 0; r < 16; ++r) z16[r] = 0.f;
  f32x16 oacc[2][2];   // [df][qf]
  oacc[0][0] = z16; oacc[0][1] = z16; oacc[1][0] = z16; oacc[1][1] = z16;
  float lpart[2] = {0.f, 0.f};

  // K/V chunk loader: global -> registers (per-lane 16B contiguous, L2-resident)
  auto LK = [&](int i, bf16x8 (&kk)[4], bf16x8 (&vv)[4]) {
    const int kv0 = (w + 4 * i) * 32;
    #pragma unroll
    for (int tq = 0; tq < 4; ++tq)
      kk[tq] = *(const bf16x8*)&Kp[(size_t)(kv0 + q31) * 64 + tq * 16 + hi * 8];
    #pragma unroll
    for (int df = 0; df < 2; ++df)
      #pragma unroll
      for (int tt = 0; tt < 2; ++tt)
        vv[df * 2 + tt] = *(const bf16x8*)&Vp[(size_t)(df * 32 + q31) * 2048 + kv0 + tt * 16 + hi * 8];
  };

  auto COMPUTE = [&](int i, bf16x8 (&kk)[4], bf16x8 (&vv)[4]) {
    const int kv0 = (w + 4 * i) * 32;
    float4 bias[4];
    #pragma unroll
    for (int g = 0; g < 4; ++g)
      bias[g] = *(const float4*)&brow[kv0 + g * 8 + hi * 4];

    #pragma unroll
    for (int qf = 0; qf < 2; ++qf) {
      // S^T = K * Q^T ; persistent zero C (no mov-init)
      f32x16 sacc;
      __builtin_amdgcn_s_setprio(1);
      sacc = __builtin_amdgcn_mfma_f32_32x32x16_bf16(kk[0], qfr[qf][0], z16, 0, 0, 0);
      #pragma unroll
      for (int tq = 1; tq < 4; ++tq)
        sacc = __builtin_amdgcn_mfma_f32_32x32x16_bf16(kk[tq], qfr[qf][tq], sacc, 0, 0, 0);
      __builtin_amdgcn_s_setprio(0);

      // e = exp2(s + maskbias); kv-rel row of reg r = (r&3) + 8*(r>>2) + 4*hi
      float e[16];
      #pragma unroll
      for (int g = 0; g < 4; ++g) {
        e[g*4+0] = __builtin_amdgcn_exp2f(sacc[g*4+0] + bias[g].x);
        e[g*4+1] = __builtin_amdgcn_exp2f(sacc[g*4+1] + bias[g].y);
        e[g*4+2] = __builtin_amdgcn_exp2f(sacc[g*4+2] + bias[g].z);
        e[g*4+3] = __builtin_amdgcn_exp2f(sacc[g*4+3] + bias[g].w);
      }
      // tree sum (depth 4)
      {
        float s0 = e[0]+e[1], s1 = e[2]+e[3], s2 = e[4]+e[5], s3 = e[6]+e[7];
        float s4 = e[8]+e[9], s5 = e[10]+e[11], s6 = e[12]+e[13], s7 = e[14]+e[15];
        float t0 = s0+s1, t1 = s2+s3, t2 = s4+s5, t3 = s6+s7;
        lpart[qf] += (t0+t1) + (t2+t3);
      }

      // pack + permlane32_swap: PV B-operand in registers (T12)
      unsigned int W[8];
      #pragma unroll
      for (int j = 0; j < 8; ++j) W[j] = cvtpk(e[2*j], e[2*j+1]);
      asm("v_permlane32_swap_b32 %0, %1" : "+v"(W[0]), "+v"(W[2]));
      asm("v_permlane32_swap_b32 %0, %1" : "+v"(W[1]), "+v"(W[3]));
      asm("v_permlane32_swap_b32 %0, %1" : "+v"(W[4]), "+v"(W[6]));
      asm("v_permlane32_swap_b32 %0, %1" : "+v"(W[5]), "+v"(W[7]));
      u32x4 lo4 = {W[0], W[1], W[2], W[3]};
      u32x4 hi4 = {W[4], W[5], W[6], W[7]};
      bf16x8 pb0 = __builtin_bit_cast(bf16x8, lo4);
      bf16x8 pb1 = __builtin_bit_cast(bf16x8, hi4);

      __builtin_amdgcn_s_setprio(1);
      oacc[0][qf] = __builtin_amdgcn_mfma_f32_32x32x16_bf16(vv[0], pb0, oacc[0][qf], 0, 0, 0);
      oacc[0][qf] = __builtin_amdgcn_mfma_f32_32x32x16_bf16(vv[1], pb1, oacc[0][qf], 0, 0, 0);
      oacc[1][qf] = __builtin_amdgcn_mfma_f32_32x32x16_bf16(vv[2], pb0, oacc[1][qf], 0, 0, 0);
      oacc[1][qf] = __builtin_amdgcn_mfma_f32_32x32x16_bf16(vv[3], pb1, oacc[1][qf], 0, 0, 0);
      __builtin_amdgcn_s_setprio(0);
    }
  };

  // depth-1 register double-buffer: loads for chunk i+1 in flight under compute of i
  bf16x8 kA[4], vA[4], kB[4], vB[4];
  LK(0, kA, vA);
  for (int ii = 0; ii < 8; ++ii) {
    LK(2 * ii + 1, kB, vB);
    COMPUTE(2 * ii, kA, vA);
    if (ii < 7) LK(2 * ii + 2, kA, vA);
    COMPUTE(2 * ii + 1, kB, vB);
  }

  // ---- cross-wave combine: O = sum_w O_w, l = sum_w l_w (verified R5) ----
  float* pc = (float*)lds_all;                 // [w][q 64][68 floats] (padded stride)
  float* ls = (float*)(lds_all + 69632);       // [w][q 64]
  #pragma unroll
  for (int qf = 0; qf < 2; ++qf) {
    float lfull = lpart[qf] + __shfl_xor(lpart[qf], 32);
    int qq = qf * 32 + q31;
    if (hi == 0) ls[w * 64 + qq] = lfull;
    #pragma unroll
    for (int df = 0; df < 2; ++df)
      #pragma unroll
      for (int g = 0; g < 4; ++g) {
        f32x4 v4 = {oacc[df][qf][g*4+0], oacc[df][qf][g*4+1],
                    oacc[df][qf][g*4+2], oacc[df][qf][g*4+3]};
        *(f32x4*)&pc[w * 4352 + qq * 68 + df * 32 + g * 8 + hi * 4] = v4;
      }
  }
  __syncthreads();
  {
    const int q = t >> 2, ds = (t & 3) * 16;
    float lsumv = ls[q] + ls[64 + q] + ls[128 + q] + ls[192 + q];
    f32x4 o4[4];
    #pragma unroll
    for (int j = 0; j < 4; ++j) o4[j] = *(const f32x4*)&pc[q * 68 + ds + j * 4];
    #pragma unroll
    for (int ww = 1; ww < 4; ++ww)
      #pragma unroll
      for (int j = 0; j < 4; ++j) {
        f32x4 p4 = *(const f32x4*)&pc[ww * 4352 + q * 68 + ds + j * 4];
        o4[j] += p4;
      }
    float rinv = __builtin_amdgcn_rcpf(lsumv);
    unsigned int pk[8];
    #pragma unroll
    for (int j = 0; j < 4; ++j) {
      pk[2*j]   = cvtpk(o4[j][0] * rinv, o4[j][1] * rinv);
      pk[2*j+1] = cvtpk(o4[j][2] * rinv, o4[j][3] * rinv);
    }
    unsigned short* dst = &OT[((size_t)b * 2048 + nt * 64 + q) * 512 + h * 64 + ds];
    u32x4 s0 = {pk[0], pk[1], pk[2], pk[3]};
    u32x4 s1 = {pk[4], pk[5], pk[6], pk[7]};
    *(u32x4*)dst = s0;
    *(u32x4*)(dst + 8) = s1;
  }
}

// --------- fused: final projection + bias + f32 residual + channel-LN + transposed store ---------
__global__ __launch_bounds__(256) void k_out(
    const unsigned short* __restrict__ OT, const unsigned short* __restrict__ wmw,
    const float* __restrict__ bm, const float* __restrict__ fq,
    const float* __restrict__ g, const float* __restrict__ be,
    float* __restrict__ out)
{
  const int b = blockIdx.y;
  const int n0 = blockIdx.x * 32;
  const int t = threadIdx.x, w = t >> 6, l = t & 63, q = l >> 4, m16 = l & 15;

  __shared__ __attribute__((aligned(16))) unsigned short As[2][2048];    // 2 x 4 KB
  __shared__ __attribute__((aligned(16))) unsigned short Bs[2][32768];   // 2 x 64 KB
  __shared__ float ssum[4][32], ssq[4][32];

  f32x4 acc[2][8];
  const f32x4 fz = {0.f, 0.f, 0.f, 0.f};
  #pragma unroll
  for (int mf = 0; mf < 2; ++mf)
    #pragma unroll
    for (int nf = 0; nf < 8; ++nf) acc[mf][nf] = fz;

  const unsigned short* Abase = OT + ((size_t)b * 2048 + n0) * 512;
  const unsigned short* Bbase = wmw;

#define OUT_STAGE(BUF, KS)                                                          \
  {                                                                                 \
    { int row = t >> 3, j = t & 7;                                                  \
      gl_lds16(Abase + (size_t)row * 512 + (KS) * 64 + ((j ^ (row & 7)) * 8),       \
               (char*)As[BUF] + w * 1024); }                                        \
    _Pragma("unroll")                                                               \
    for (int c = 0; c < 16; ++c) {                                                  \
      int slot = c * 256 + t;                                                       \
      int row = slot >> 3, j = slot & 7;                                            \
      gl_lds16(Bbase + (size_t)row * 512 + (KS) * 64 + ((j ^ (row & 7)) * 8),       \
               (char*)Bs[BUF] + (c * 256 + w * 64) * 16);                           \
    }                                                                               \
  }

  OUT_STAGE(0, 0)
  asm volatile("s_waitcnt vmcnt(0)" ::: "memory");
  __syncthreads();

  for (int ks = 0; ks < 8; ++ks) {
    const int cur = ks & 1;
    if (ks < 7) OUT_STAGE(cur ^ 1, ks + 1)
    #pragma unroll
    for (int kk = 0; kk < 2; ++kk) {
      bf16x8 av[2];
      #pragma unroll
      for (int mf = 0; mf < 2; ++mf) {
        int row = mf * 16 + m16;
        av[mf] = *(const bf16x8*)((const char*)As[cur] + row * 128 + (((kk * 4 + q) ^ (row & 7)) * 16));
      }
      #pragma unroll
      for (int nf = 0; nf < 8; ++nf) {
        int row = w * 128 + nf * 16 + m16;
        bf16x8 bv = *(const bf16x8*)((const char*)Bs[cur] + row * 128 + (((kk * 4 + q) ^ (row & 7)) * 16));
        acc[0][nf] = __builtin_amdgcn_mfma_f32_16x16x32_bf16(av[0], bv, acc[0][nf], 0, 0, 0);
        acc[1][nf] = __builtin_amdgcn_mfma_f32_16x16x32_bf16(av[1], bv, acc[1][nf], 0, 0, 0);
      }
    }
    if (ks < 7) {
      asm volatile("s_waitcnt vmcnt(0)" ::: "memory");
      __syncthreads();
    }
  }
#undef OUT_STAGE

  float gv[8], bev[8], bmv[8];
  #pragma unroll
  for (int nf = 0; nf < 8; ++nf) {
    int c = w * 128 + nf * 16 + m16;
    gv[nf] = g[c]; bev[nf] = be[c]; bmv[nf] = bm[c];
  }
  #pragma unroll
  for (int mf = 0; mf < 2; ++mf)
    #pragma unroll
    for (int nf = 0; nf < 8; ++nf) {
      int c = w * 128 + nf * 16 + m16;
      f32x4 res = *(const f32x4*)&fq[((size_t)b * 512 + c) * 2048 + n0 + mf * 16 + q * 4];
      #pragma unroll
      for (int r = 0; r < 4; ++r)
        acc[mf][nf][r] += bmv[nf] + res[r];
    }
  #pragma unroll
  for (int mf = 0; mf < 2; ++mf)
    #pragma unroll
    for (int r = 0; r < 4; ++r) {
      float ps = 0.f, pss = 0.f;
      #pragma unroll
      for (int nf = 0; nf < 8; ++nf) {
        float v = acc[mf][nf][r];
        ps += v; pss += v * v;
      }
      ps += __shfl_xor(ps, 1); pss += __shfl_xor(pss, 1);
      ps += __shfl_xor(ps, 2); pss += __shfl_xor(pss, 2);
      ps += __shfl_xor(ps, 4); pss += __shfl_xor(pss, 4);
      ps += __shfl_xor(ps, 8); pss += __shfl_xor(pss, 8);
      if (m16 == 0) {
        ssum[w][mf * 16 + q * 4 + r] = ps;
        ssq[w][mf * 16 + q * 4 + r] = pss;
      }
    }
  __syncthreads();
  #pragma unroll
  for (int mf = 0; mf < 2; ++mf)
    #pragma unroll
    for (int r = 0; r < 4; ++r) {
      int nl = mf * 16 + q * 4 + r;
      float S  = ssum[0][nl] + ssum[1][nl] + ssum[2][nl] + ssum[3][nl];
      float SS = ssq[0][nl] + ssq[1][nl] + ssq[2][nl] + ssq[3][nl];
      float mu = S * (1.f / 512.f);
      float var = SS * (1.f / 512.f) - mu * mu;
      float rstd = rsqrtf(var + 1e-5f);
      #pragma unroll
      for (int nf = 0; nf < 8; ++nf)
        acc[mf][nf][r] = (acc[mf][nf][r] - mu) * rstd * gv[nf] + bev[nf];
    }
  #pragma unroll
  for (int mf = 0; mf < 2; ++mf)
    #pragma unroll
    for (int nf = 0; nf < 8; ++nf) {
      int c = w * 128 + nf * 16 + m16;
      *(f32x4*)&out[((size_t)b * 512 + c) * 2048 + n0 + mf * 16 + q * 4] = acc[mf][nf];
    }
}

// ---------------- launcher ----------------
extern "C" void kernel_launch(void* const* d_in, const int* in_sizes, int n_in,
                              void* d_out, int out_size, void* d_ws, size_t ws_size,
                              hipStream_t stream) {
  const float* fq  = (const float*)d_in[0];
  const float* fk  = (const float*)d_in[1];
  const int*   msk = (const int*)d_in[2];
  const float* Wq  = (const float*)d_in[3];
  const float* bq  = (const float*)d_in[4];
  const float* Wk  = (const float*)d_in[5];
  const float* bk  = (const float*)d_in[6];
  const float* Wf  = (const float*)d_in[7];
  const float* bfv = (const float*)d_in[8];
  const float* Wm  = (const float*)d_in[9];
  const float* bm  = (const float*)d_in[10];
  const float* lng = (const float*)d_in[11];
  const float* lnb = (const float*)d_in[12];
  float* out = (float*)d_out;

  char* ws = (char*)d_ws;
  const size_t MB = 1024 * 1024;
  unsigned short* xqt = (unsigned short*)(ws + 0 * MB);        // 4 MB  [b][n][512] bf16
  unsigned short* xkt = (unsigned short*)(ws + 4 * MB);        // 4 MB
  unsigned short* wqb = (unsigned short*)(ws + 8 * MB);        // 512 KB
  unsigned short* wkb = (unsigned short*)(ws + 8 * MB + 512 * 1024);
  unsigned short* wfb = (unsigned short*)(ws + 9 * MB);
  unsigned short* wmb = (unsigned short*)(ws + 9 * MB + 512 * 1024);
  unsigned short* Qb  = (unsigned short*)(ws + 10 * MB);       // 4 MB  [bh][n][64]
  unsigned short* Kb  = (unsigned short*)(ws + 14 * MB);       // 4 MB  [bh][m][64]
  unsigned short* VTb = (unsigned short*)(ws + 18 * MB);       // 4 MB  [bh][64][m]
  unsigned short* OTb = (unsigned short*)(ws + 22 * MB);       // 4 MB  [b][n][512]
  float*          biasf = (float*)(ws + 26 * MB);              // 16 KB

  hipLaunchKernelGGL(k_pre, dim3(3088), dim3(256), 0, stream,
                     fq, fk, Wq, Wk, Wf, Wm, msk, xqt, xkt, wqb, wkb, wfb, wmb, biasf);
  hipLaunchKernelGGL(k_proj, dim3(384), dim3(256), 0, stream,
                     xqt, xkt, wqb, wkb, wfb, bq, bk, bfv, Qb, Kb, VTb);
  hipLaunchKernelGGL(k_attn4, dim3(512), dim3(256), 0, stream, Qb, Kb, VTb, biasf, OTb);
  hipLaunchKernelGGL(k_out, dim3(64, 2), dim3(256), 0, stream,
                     OTb, wmb, bm, fq, lng, lnb, out);
}

// Round 8
// 83.350 us; speedup vs baseline: 1.0769x; 1.0068x over previous
//
#include <hip/hip_runtime.h>
#include <hip/hip_bf16.h>

// B=2, D=512, N=2048, H=8, head=64.

using bf16x8 = __attribute__((ext_vector_type(8))) __bf16;
using f32x4  = __attribute__((ext_vector_type(4))) float;
using f32x16 = __attribute__((ext_vector_type(16))) float;
using us8    = __attribute__((ext_vector_type(8))) unsigned short;
using u32x4  = __attribute__((ext_vector_type(4))) unsigned int;

__device__ __forceinline__ unsigned short f2b(float f) {
  unsigned int u = __builtin_bit_cast(unsigned int, f);
  u += 0x7fffu + ((u >> 16) & 1u);
  return (unsigned short)(u >> 16);
}
__device__ __forceinline__ float b2f(unsigned short s) {
  unsigned int u = ((unsigned int)s) << 16;
  return __builtin_bit_cast(float, u);
}
__device__ __forceinline__ unsigned int cvtpk(float lo, float hi) {
  unsigned int w;
  asm("v_cvt_pk_bf16_f32 %0, %1, %2" : "=v"(w) : "v"(lo), "v"(hi));
  return w;
}
__device__ __forceinline__ void gl_lds16(const void* g, void* l) {
  __builtin_amdgcn_global_load_lds((const __attribute__((address_space(1))) void*)g,
                                   (__attribute__((address_space(3))) void*)l, 16, 0, 0);
}

// ------- fused pre-pass: feats transpose (f32->bf16) + weight permute + mask bitmap -------
__global__ __launch_bounds__(256) void k_pre(
    const float* __restrict__ fq, const float* __restrict__ fk,
    const float* __restrict__ Wq, const float* __restrict__ Wk,
    const float* __restrict__ Wf, const float* __restrict__ Wm,
    const int* __restrict__ mask,
    unsigned short* __restrict__ xqt, unsigned short* __restrict__ xkt,
    unsigned short* __restrict__ wqb, unsigned short* __restrict__ wkb,
    unsigned short* __restrict__ wfb, unsigned short* __restrict__ wmb,
    unsigned int* __restrict__ mbits)
{
  const int id = blockIdx.x;
  const int t = threadIdx.x;
  __shared__ float tile[64][65];

  if (id < 1024) {
    const int which = id >> 9;
    const int b = (id >> 8) & 1;
    const int i0 = ((id >> 5) & 7) * 64;
    const int n0 = (id & 31) * 64;
    const float* __restrict__ src = which ? fk : fq;
    unsigned short* __restrict__ dst = which ? xkt : xqt;
    const int cl = t & 63, rw = t >> 6;
    #pragma unroll
    for (int rr = 0; rr < 16; ++rr) {
      int il = rr * 4 + rw;
      tile[il][cl] = src[((size_t)b * 512 + i0 + il) * 2048 + n0 + cl];
    }
    __syncthreads();
    const int ci = (t & 31) * 2, rhalf = t >> 5;
    #pragma unroll
    for (int rr = 0; rr < 8; ++rr) {
      int nl = rr * 8 + rhalf;
      unsigned int v = (unsigned int)f2b(tile[ci][nl]) |
                       ((unsigned int)f2b(tile[ci + 1][nl]) << 16);
      *(unsigned int*)&dst[((size_t)b * 2048 + n0 + nl) * 512 + i0 + ci] = v;
    }
  } else if (id < 3072) {
    const int r = id - 1024;
    const int mat = r >> 9, cp = r & 511;
    if (mat < 3) {
      const float* W = (mat == 0) ? Wq : (mat == 1) ? Wk : Wf;
      unsigned short* O = (mat == 0) ? wqb : (mat == 1) ? wkb : wfb;
      const int orig = (cp & 63) * 8 + (cp >> 6);   // d*8+h
      for (int j = t; j < 512; j += 256)
        O[cp * 512 + j] = f2b(W[orig * 512 + j]);
    } else {
      for (int j = t; j < 512; j += 256) {
        int h = j >> 6, d = j & 63;
        wmb[cp * 512 + j] = f2b(Wm[cp * 512 + d * 8 + h]);
      }
    }
  } else {
    // mask bitmap: 2 b x 64 u32 words (bit j of word w = mask[b][w*32+j])
    if (t < 128) {
      int bb = t >> 6, wd = t & 63;
      unsigned int v = 0;
      #pragma unroll
      for (int j = 0; j < 32; ++j)
        v |= (mask[bb * 2048 + wd * 32 + j] ? 1u : 0u) << j;
      mbits[t] = v;
    }
  }
}

// ---------------- QKV projections: 128x128 NT, gl_lds 2-phase double-buffer ----------------
__global__ __launch_bounds__(256) void k_proj(
    const unsigned short* __restrict__ xqt, const unsigned short* __restrict__ xkt,
    const unsigned short* __restrict__ wqp, const unsigned short* __restrict__ wkp,
    const unsigned short* __restrict__ wfp,
    const float* __restrict__ bq, const float* __restrict__ bk, const float* __restrict__ bfv,
    unsigned short* __restrict__ Qb, unsigned short* __restrict__ Kb, unsigned short* __restrict__ VTb)
{
  const int lid = blockIdx.x;                     // 0..383
  const int orig = (lid & 7) * 48 + (lid >> 3);   // bijective (384 = 8*48)
  const int z = orig >> 6;
  const int bid = orig & 63;
  const int b = z / 3, proj = z % 3;
  const int t = threadIdx.x, w = t >> 6, l = t & 63, q = l >> 4, m16 = l & 15;
  const int wm = w >> 1, wn = w & 1;

  __shared__ __attribute__((aligned(16))) unsigned short As[2][8192];
  __shared__ __attribute__((aligned(16))) unsigned short Bs[2][8192];

  const unsigned short* A;
  const unsigned short* Bt;
  int mt, nt_;
  if (proj < 2) {
    mt = bid >> 2; nt_ = bid & 3;
    A  = (proj == 0 ? xqt : xkt) + (size_t)b * 2048 * 512 + (size_t)mt * 128 * 512;
    Bt = (proj == 0 ? wqp : wkp) + (size_t)nt_ * 128 * 512;
  } else {
    mt = bid & 3; nt_ = bid >> 2;
    A  = wfp + (size_t)mt * 128 * 512;
    Bt = xkt + (size_t)b * 2048 * 512 + (size_t)nt_ * 128 * 512;
  }

  f32x4 acc[4][4];
  const f32x4 fz = {0.f, 0.f, 0.f, 0.f};
  #pragma unroll
  for (int mf = 0; mf < 4; ++mf)
    #pragma unroll
    for (int nf = 0; nf < 4; ++nf) acc[mf][nf] = fz;

#define PROJ_STAGE(BUF, KS)                                                          \
  {                                                                                  \
    _Pragma("unroll")                                                                \
    for (int c = 0; c < 4; ++c) {                                                    \
      int slot = c * 256 + t;                                                        \
      int row = slot >> 3, j = slot & 7;                                             \
      int jj = j ^ (row & 7);                                                        \
      gl_lds16(A  + (size_t)row * 512 + (KS) * 64 + jj * 8,                          \
               (char*)As[BUF] + (c * 256 + w * 64) * 16);                            \
      gl_lds16(Bt + (size_t)row * 512 + (KS) * 64 + jj * 8,                          \
               (char*)Bs[BUF] + (c * 256 + w * 64) * 16);                            \
    }                                                                                \
  }

  PROJ_STAGE(0, 0)
  asm volatile("s_waitcnt vmcnt(0)" ::: "memory");
  __syncthreads();

  for (int ks = 0; ks < 8; ++ks) {
    const int cur = ks & 1;
    if (ks < 7) PROJ_STAGE(cur ^ 1, ks + 1)
    #pragma unroll
    for (int kk = 0; kk < 2; ++kk) {
      bf16x8 av[4], bv[4];
      #pragma unroll
      for (int mf = 0; mf < 4; ++mf) {
        int row = wm * 64 + mf * 16 + m16;
        av[mf] = *(const bf16x8*)&As[cur][row * 64 + (((kk * 4 + q) ^ (row & 7)) << 3)];
      }
      #pragma unroll
      for (int nf = 0; nf < 4; ++nf) {
        int row = wn * 64 + nf * 16 + m16;
        bv[nf] = *(const bf16x8*)&Bs[cur][row * 64 + (((kk * 4 + q) ^ (row & 7)) << 3)];
      }
      #pragma unroll
      for (int mf = 0; mf < 4; ++mf)
        #pragma unroll
        for (int nf = 0; nf < 4; ++nf)
          acc[mf][nf] = __builtin_amdgcn_mfma_f32_16x16x32_bf16(av[mf], bv[nf], acc[mf][nf], 0, 0, 0);
    }
    if (ks < 7) {
      asm volatile("s_waitcnt vmcnt(0)" ::: "memory");
      __syncthreads();
    }
  }
#undef PROJ_STAGE

  const float QSCALE = 0.18033688011112042f;   // log2(e)/8 folded into Q

  if (proj < 2) {
    const float* bias = (proj == 0) ? bq : bk;
    unsigned short* dst = (proj == 0) ? Qb : Kb;
    #pragma unroll
    for (int mf = 0; mf < 4; ++mf)
      #pragma unroll
      for (int nf = 0; nf < 4; ++nf)
        #pragma unroll
        for (int r = 0; r < 4; ++r) {
          int n  = mt * 128 + wm * 64 + mf * 16 + q * 4 + r;
          int cp = nt_ * 128 + wn * 64 + nf * 16 + m16;
          int h = cp >> 6, d = cp & 63;
          float v = acc[mf][nf][r] + bias[d * 8 + h];
          if (proj == 0) v *= QSCALE;
          dst[((size_t)(b * 8 + h) * 2048 + n) * 64 + d] = f2b(v);
        }
  } else {
    #pragma unroll
    for (int mf = 0; mf < 4; ++mf)
      #pragma unroll
      for (int nf = 0; nf < 4; ++nf)
        #pragma unroll
        for (int r = 0; r < 4; ++r) {
          int cp = mt * 128 + wm * 64 + mf * 16 + q * 4 + r;
          int n  = nt_ * 128 + wn * 64 + nf * 16 + m16;
          int h = cp >> 6, d = cp & 63;
          float v = acc[mf][nf][r] + bfv[d * 8 + h];
          VTb[((size_t)(b * 8 + h) * 64 + d) * 2048 + n] = f2b(v);
        }
  }
}

// ---- flash attention v5: QBLK=128, q-split waves, shared-KV LDS pipeline, counted vmcnt ----
// 256 blocks (XCD-swizzled: 2 bh/XCD, KV L2-resident; traffic 128 MB). 64-row KV chunks
// double-buffered (32 KB); raw s_barrier (no drain); vmcnt(4) keeps next chunk in flight.
// Mask applied via wave-uniform bitmap (s_load) -> exact zeros, no vector loads in loop.
__global__ __launch_bounds__(256) void k_attn5(
    const unsigned short* __restrict__ Qb, const unsigned short* __restrict__ Kb,
    const unsigned short* __restrict__ VTb, const unsigned int* __restrict__ mbits,
    unsigned short* __restrict__ OT)
{
  const int lid = blockIdx.x;                      // 0..255
  const int orig = (lid & 7) * 32 + (lid >> 3);    // bijective (256 = 8*32)
  const int bh = orig >> 4, b = bh >> 3, h = bh & 7;
  const int qt = orig & 15;
  const int t = threadIdx.x, w = t >> 6, l = t & 63;
  const int q31 = l & 31, hi = l >> 5;

  __shared__ __attribute__((aligned(16))) char lds_all[32768];
  char* kst = lds_all;            // K: [2][64 rows][128 B], swizzled slots
  char* vst = lds_all + 16384;    // V: [2][64 rows][128 B]

  const unsigned short* Kp = Kb + (size_t)bh * (2048 * 64);
  const unsigned short* Vp = VTb + (size_t)bh * (64 * 2048);
  const unsigned int* mrow = mbits + b * 64;
  const int qbase = qt * 128 + w * 32;

  // Q fragments (B-operand): lane holds Q[qbase+q31][tq*16+hi*8+j]
  bf16x8 qfr[4];
  {
    const unsigned short* Qp = Qb + ((size_t)bh * 2048 + qbase) * 64;
    #pragma unroll
    for (int tq = 0; tq < 4; ++tq)
      qfr[tq] = *(const bf16x8*)&Qp[q31 * 64 + tq * 16 + hi * 8];
  }

  f32x16 z16;
  #pragma unroll
  for (int r = 0; r < 16; ++r) z16[r] = 0.f;
  f32x16 oacc[2];
  oacc[0] = z16; oacc[1] = z16;
  float lpart = 0.f;

  // cooperative stage: 4 gl_lds/thread (2 K + 2 V), rule-21 pre-swizzled source
#define ATT_STAGE(BUF, KV0)                                                            \
  {                                                                                    \
    _Pragma("unroll")                                                                  \
    for (int c = 0; c < 2; ++c) {                                                      \
      int s = c * 256 + t;                                                             \
      int row = s >> 3, j = s & 7;                                                     \
      gl_lds16(Kp + (size_t)((KV0) + row) * 64 + (j ^ (row & 7)) * 8,                  \
               kst + (BUF) * 8192 + (c * 256 + w * 64) * 16);                          \
    }                                                                                  \
    _Pragma("unroll")                                                                  \
    for (int c = 0; c < 2; ++c) {                                                      \
      int s = c * 256 + t;                                                             \
      int row = s >> 3, j = s & 7;                                                     \
      gl_lds16(Vp + (size_t)row * 2048 + (KV0) + (j ^ (row & 7)) * 8,                  \
               vst + (BUF) * 8192 + (c * 256 + w * 64) * 16);                          \
    }                                                                                  \
  }

  ATT_STAGE(0, 0)

  for (int i = 0; i < 32; ++i) {
    const int cur = i & 1;
    if (i < 31) {
      ATT_STAGE(cur ^ 1, (i + 1) * 64)
      asm volatile("s_waitcnt vmcnt(4)" ::: "memory");   // chunk i staged; i+1 in flight
    } else {
      asm volatile("s_waitcnt vmcnt(0)" ::: "memory");
    }
    asm volatile("s_barrier" ::: "memory");              // buf valid for all waves

    const char* kb = kst + cur * 8192;
    const char* vb = vst + cur * 8192;

    #pragma unroll
    for (int ksub = 0; ksub < 2; ++ksub) {
      const unsigned int mw2 = mrow[i * 2 + ksub] >> (hi * 4);   // wave-uniform word, lane shift

      // K fragments (A-operand): K[ksub*32+q31][tq*16+hi*8+j]
      bf16x8 ak[4];
      #pragma unroll
      for (int tq = 0; tq < 4; ++tq)
        ak[tq] = *(const bf16x8*)(kb + (ksub * 32 + q31) * 128 + (((tq * 2 + hi) ^ (q31 & 7)) * 16));

      f32x16 sacc;
      __builtin_amdgcn_s_setprio(1);
      sacc = __builtin_amdgcn_mfma_f32_32x32x16_bf16(ak[0], qfr[0], z16, 0, 0, 0);
      #pragma unroll
      for (int tq = 1; tq < 4; ++tq)
        sacc = __builtin_amdgcn_mfma_f32_32x32x16_bf16(ak[tq], qfr[tq], sacc, 0, 0, 0);
      __builtin_amdgcn_s_setprio(0);

      // e = exp2(s), zeroed for masked kv (bit kvrel of mw2; kvrel = r2 + 8g + 4hi)
      float e[16];
      #pragma unroll
      for (int g = 0; g < 4; ++g)
        #pragma unroll
        for (int r2 = 0; r2 < 4; ++r2) {
          float ev = __builtin_amdgcn_exp2f(sacc[g * 4 + r2]);
          e[g * 4 + r2] = ((mw2 >> (r2 + 8 * g)) & 1u) ? ev : 0.f;
        }
      {
        float s0 = e[0]+e[1], s1 = e[2]+e[3], s2 = e[4]+e[5], s3 = e[6]+e[7];
        float s4 = e[8]+e[9], s5 = e[10]+e[11], s6 = e[12]+e[13], s7 = e[14]+e[15];
        float t0 = s0+s1, t1 = s2+s3, t2 = s4+s5, t3 = s6+s7;
        lpart += (t0+t1) + (t2+t3);
      }

      // pack + permlane32_swap: PV B-operand in registers (T12)
      unsigned int W[8];
      #pragma unroll
      for (int j = 0; j < 8; ++j) W[j] = cvtpk(e[2*j], e[2*j+1]);
      asm("v_permlane32_swap_b32 %0, %1" : "+v"(W[0]), "+v"(W[2]));
      asm("v_permlane32_swap_b32 %0, %1" : "+v"(W[1]), "+v"(W[3]));
      asm("v_permlane32_swap_b32 %0, %1" : "+v"(W[4]), "+v"(W[6]));
      asm("v_permlane32_swap_b32 %0, %1" : "+v"(W[5]), "+v"(W[7]));
      u32x4 lo4 = {W[0], W[1], W[2], W[3]};
      u32x4 hi4 = {W[4], W[5], W[6], W[7]};
      bf16x8 pb0 = __builtin_bit_cast(bf16x8, lo4);
      bf16x8 pb1 = __builtin_bit_cast(bf16x8, hi4);

      // V fragments (A-operand): V^T[df*32+q31][ksub*32 + tt*16 + hi*8 + j]
      bf16x8 av00 = *(const bf16x8*)(vb + q31 * 128 + (((ksub * 4 + 0 * 2 + hi) ^ (q31 & 7)) * 16));
      bf16x8 av01 = *(const bf16x8*)(vb + q31 * 128 + (((ksub * 4 + 1 * 2 + hi) ^ (q31 & 7)) * 16));
      bf16x8 av10 = *(const bf16x8*)(vb + (32 + q31) * 128 + (((ksub * 4 + 0 * 2 + hi) ^ (q31 & 7)) * 16));
      bf16x8 av11 = *(const bf16x8*)(vb + (32 + q31) * 128 + (((ksub * 4 + 1 * 2 + hi) ^ (q31 & 7)) * 16));

      __builtin_amdgcn_s_setprio(1);
      oacc[0] = __builtin_amdgcn_mfma_f32_32x32x16_bf16(av00, pb0, oacc[0], 0, 0, 0);
      oacc[0] = __builtin_amdgcn_mfma_f32_32x32x16_bf16(av01, pb1, oacc[0], 0, 0, 0);
      oacc[1] = __builtin_amdgcn_mfma_f32_32x32x16_bf16(av10, pb0, oacc[1], 0, 0, 0);
      oacc[1] = __builtin_amdgcn_mfma_f32_32x32x16_bf16(av11, pb1, oacc[1], 0, 0, 0);
      __builtin_amdgcn_s_setprio(0);
    }

    asm volatile("s_barrier" ::: "memory");   // all waves done reading buf before restage
  }
#undef ATT_STAGE

  // epilogue: normalize, transpose via wave-private LDS (4 KB each), coalesced store
  unsigned short* ot = (unsigned short*)(lds_all + w * 4096);   // [32 q][64 d] swizzled
  {
    float ls = lpart + __shfl_xor(lpart, 32);
    float rinv = __builtin_amdgcn_rcpf(ls);
    #pragma unroll
    for (int df = 0; df < 2; ++df)
      #pragma unroll
      for (int rg = 0; rg < 4; ++rg)
        #pragma unroll
        for (int pr = 0; pr < 2; ++pr) {
          int r0 = rg * 4 + pr * 2;
          unsigned int wv = cvtpk(oacc[df][r0] * rinv, oacc[df][r0 + 1] * rinv);
          *(unsigned int*)((char*)ot + q31 * 128 + (((df * 4 + rg) ^ (q31 & 7)) * 16) + hi * 8 + pr * 4) = wv;
        }
  }
  #pragma unroll
  for (int j = 0; j < 4; ++j) {
    int qq = j * 8 + (l >> 3);
    int sl = l & 7;
    us8 val = *(const us8*)((const char*)ot + qq * 128 + ((sl ^ (qq & 7)) * 16));
    *(us8*)&OT[((size_t)b * 2048 + qbase + qq) * 512 + h * 64 + sl * 8] = val;
  }
}

// --------- fused: final projection + bias + f32 residual + channel-LN + transposed store ---------
__global__ __launch_bounds__(256) void k_out(
    const unsigned short* __restrict__ OT, const unsigned short* __restrict__ wmw,
    const float* __restrict__ bm, const float* __restrict__ fq,
    const float* __restrict__ g, const float* __restrict__ be,
    float* __restrict__ out)
{
  const int b = blockIdx.y;
  const int n0 = blockIdx.x * 32;
  const int t = threadIdx.x, w = t >> 6, l = t & 63, q = l >> 4, m16 = l & 15;

  __shared__ __attribute__((aligned(16))) unsigned short As[2][2048];    // 2 x 4 KB
  __shared__ __attribute__((aligned(16))) unsigned short Bs[2][32768];   // 2 x 64 KB
  __shared__ float ssum[4][32], ssq[4][32];

  f32x4 acc[2][8];
  const f32x4 fz = {0.f, 0.f, 0.f, 0.f};
  #pragma unroll
  for (int mf = 0; mf < 2; ++mf)
    #pragma unroll
    for (int nf = 0; nf < 8; ++nf) acc[mf][nf] = fz;

  const unsigned short* Abase = OT + ((size_t)b * 2048 + n0) * 512;
  const unsigned short* Bbase = wmw;

#define OUT_STAGE(BUF, KS)                                                          \
  {                                                                                 \
    { int row = t >> 3, j = t & 7;                                                  \
      gl_lds16(Abase + (size_t)row * 512 + (KS) * 64 + ((j ^ (row & 7)) * 8),       \
               (char*)As[BUF] + w * 1024); }                                        \
    _Pragma("unroll")                                                               \
    for (int c = 0; c < 16; ++c) {                                                  \
      int slot = c * 256 + t;                                                       \
      int row = slot >> 3, j = slot & 7;                                            \
      gl_lds16(Bbase + (size_t)row * 512 + (KS) * 64 + ((j ^ (row & 7)) * 8),       \
               (char*)Bs[BUF] + (c * 256 + w * 64) * 16);                           \
    }                                                                               \
  }

  OUT_STAGE(0, 0)
  asm volatile("s_waitcnt vmcnt(0)" ::: "memory");
  __syncthreads();

  for (int ks = 0; ks < 8; ++ks) {
    const int cur = ks & 1;
    if (ks < 7) OUT_STAGE(cur ^ 1, ks + 1)
    #pragma unroll
    for (int kk = 0; kk < 2; ++kk) {
      bf16x8 av[2];
      #pragma unroll
      for (int mf = 0; mf < 2; ++mf) {
        int row = mf * 16 + m16;
        av[mf] = *(const bf16x8*)((const char*)As[cur] + row * 128 + (((kk * 4 + q) ^ (row & 7)) * 16));
      }
      #pragma unroll
      for (int nf = 0; nf < 8; ++nf) {
        int row = w * 128 + nf * 16 + m16;
        bf16x8 bv = *(const bf16x8*)((const char*)Bs[cur] + row * 128 + (((kk * 4 + q) ^ (row & 7)) * 16));
        acc[0][nf] = __builtin_amdgcn_mfma_f32_16x16x32_bf16(av[0], bv, acc[0][nf], 0, 0, 0);
        acc[1][nf] = __builtin_amdgcn_mfma_f32_16x16x32_bf16(av[1], bv, acc[1][nf], 0, 0, 0);
      }
    }
    if (ks < 7) {
      asm volatile("s_waitcnt vmcnt(0)" ::: "memory");
      __syncthreads();
    }
  }
#undef OUT_STAGE

  float gv[8], bev[8], bmv[8];
  #pragma unroll
  for (int nf = 0; nf < 8; ++nf) {
    int c = w * 128 + nf * 16 + m16;
    gv[nf] = g[c]; bev[nf] = be[c]; bmv[nf] = bm[c];
  }
  #pragma unroll
  for (int mf = 0; mf < 2; ++mf)
    #pragma unroll
    for (int nf = 0; nf < 8; ++nf) {
      int c = w * 128 + nf * 16 + m16;
      f32x4 res = *(const f32x4*)&fq[((size_t)b * 512 + c) * 2048 + n0 + mf * 16 + q * 4];
      #pragma unroll
      for (int r = 0; r < 4; ++r)
        acc[mf][nf][r] += bmv[nf] + res[r];
    }
  #pragma unroll
  for (int mf = 0; mf < 2; ++mf)
    #pragma unroll
    for (int r = 0; r < 4; ++r) {
      float ps = 0.f, pss = 0.f;
      #pragma unroll
      for (int nf = 0; nf < 8; ++nf) {
        float v = acc[mf][nf][r];
        ps += v; pss += v * v;
      }
      ps += __shfl_xor(ps, 1); pss += __shfl_xor(pss, 1);
      ps += __shfl_xor(ps, 2); pss += __shfl_xor(pss, 2);
      ps += __shfl_xor(ps, 4); pss += __shfl_xor(pss, 4);
      ps += __shfl_xor(ps, 8); pss += __shfl_xor(pss, 8);
      if (m16 == 0) {
        ssum[w][mf * 16 + q * 4 + r] = ps;
        ssq[w][mf * 16 + q * 4 + r] = pss;
      }
    }
  __syncthreads();
  #pragma unroll
  for (int mf = 0; mf < 2; ++mf)
    #pragma unroll
    for (int r = 0; r < 4; ++r) {
      int nl = mf * 16 + q * 4 + r;
      float S  = ssum[0][nl] + ssum[1][nl] + ssum[2][nl] + ssum[3][nl];
      float SS = ssq[0][nl] + ssq[1][nl] + ssq[2][nl] + ssq[3][nl];
      float mu = S * (1.f / 512.f);
      float var = SS * (1.f / 512.f) - mu * mu;
      float rstd = rsqrtf(var + 1e-5f);
      #pragma unroll
      for (int nf = 0; nf < 8; ++nf)
        acc[mf][nf][r] = (acc[mf][nf][r] - mu) * rstd * gv[nf] + bev[nf];
    }
  #pragma unroll
  for (int mf = 0; mf < 2; ++mf)
    #pragma unroll
    for (int nf = 0; nf < 8; ++nf) {
      int c = w * 128 + nf * 16 + m16;
      *(f32x4*)&out[((size_t)b * 512 + c) * 2048 + n0 + mf * 16 + q * 4] = acc[mf][nf];
    }
}

// ---------------- launcher ----------------
extern "C" void kernel_launch(void* const* d_in, const int* in_sizes, int n_in,
                              void* d_out, int out_size, void* d_ws, size_t ws_size,
                              hipStream_t stream) {
  const float* fq  = (const float*)d_in[0];
  const float* fk  = (const float*)d_in[1];
  const int*   msk = (const int*)d_in[2];
  const float* Wq  = (const float*)d_in[3];
  const float* bq  = (const float*)d_in[4];
  const float* Wk  = (const float*)d_in[5];
  const float* bk  = (const float*)d_in[6];
  const float* Wf  = (const float*)d_in[7];
  const float* bfv = (const float*)d_in[8];
  const float* Wm  = (const float*)d_in[9];
  const float* bm  = (const float*)d_in[10];
  const float* lng = (const float*)d_in[11];
  const float* lnb = (const float*)d_in[12];
  float* out = (float*)d_out;

  char* ws = (char*)d_ws;
  const size_t MB = 1024 * 1024;
  unsigned short* xqt = (unsigned short*)(ws + 0 * MB);        // 4 MB  [b][n][512] bf16
  unsigned short* xkt = (unsigned short*)(ws + 4 * MB);        // 4 MB
  unsigned short* wqb = (unsigned short*)(ws + 8 * MB);        // 512 KB
  unsigned short* wkb = (unsigned short*)(ws + 8 * MB + 512 * 1024);
  unsigned short* wfb = (unsigned short*)(ws + 9 * MB);
  unsigned short* wmb = (unsigned short*)(ws + 9 * MB + 512 * 1024);
  unsigned short* Qb  = (unsigned short*)(ws + 10 * MB);       // 4 MB  [bh][n][64]
  unsigned short* Kb  = (unsigned short*)(ws + 14 * MB);       // 4 MB  [bh][m][64]
  unsigned short* VTb = (unsigned short*)(ws + 18 * MB);       // 4 MB  [bh][64][m]
  unsigned short* OTb = (unsigned short*)(ws + 22 * MB);       // 4 MB  [b][n][512]
  unsigned int*   mbits = (unsigned int*)(ws + 26 * MB);       // 512 B

  hipLaunchKernelGGL(k_pre, dim3(3073), dim3(256), 0, stream,
                     fq, fk, Wq, Wk, Wf, Wm, msk, xqt, xkt, wqb, wkb, wfb, wmb, mbits);
  hipLaunchKernelGGL(k_proj, dim3(384), dim3(256), 0, stream,
                     xqt, xkt, wqb, wkb, wfb, bq, bk, bfv, Qb, Kb, VTb);
  hipLaunchKernelGGL(k_attn5, dim3(256), dim3(256), 0, stream, Qb, Kb, VTb, mbits, OTb);
  hipLaunchKernelGGL(k_out, dim3(64, 2), dim3(256), 0, stream,
                     OTb, wmb, bm, fq, lng, lnb, out);
}

// Round 9
// 81.888 us; speedup vs baseline: 1.0962x; 1.0179x over previous
//
#include <hip/hip_runtime.h>
#include <hip/hip_bf16.h>

// B=2, D=512, N=2048, H=8, head=64.

using bf16x8 = __attribute__((ext_vector_type(8))) __bf16;
using f32x4  = __attribute__((ext_vector_type(4))) float;
using f32x16 = __attribute__((ext_vector_type(16))) float;
using us8    = __attribute__((ext_vector_type(8))) unsigned short;
using u32x4  = __attribute__((ext_vector_type(4))) unsigned int;

__device__ __forceinline__ unsigned short f2b(float f) {
  unsigned int u = __builtin_bit_cast(unsigned int, f);
  u += 0x7fffu + ((u >> 16) & 1u);
  return (unsigned short)(u >> 16);
}
__device__ __forceinline__ float b2f(unsigned short s) {
  unsigned int u = ((unsigned int)s) << 16;
  return __builtin_bit_cast(float, u);
}
__device__ __forceinline__ unsigned int cvtpk(float lo, float hi) {
  unsigned int w;
  asm("v_cvt_pk_bf16_f32 %0, %1, %2" : "=v"(w) : "v"(lo), "v"(hi));
  return w;
}
__device__ __forceinline__ void gl_lds16(const void* g, void* l) {
  __builtin_amdgcn_global_load_lds((const __attribute__((address_space(1))) void*)g,
                                   (__attribute__((address_space(3))) void*)l, 16, 0, 0);
}
// pinned 16B global load: asm volatile -> compiler cannot sink/rematerialize (attn4 lesson)
template <int OFF>
__device__ __forceinline__ bf16x8 gload16(const unsigned short* p) {
  u32x4 r;
  asm volatile("global_load_dwordx4 %0, %1, off offset:%2"
               : "=v"(r) : "v"(p), "i"(OFF) : "memory");
  return __builtin_bit_cast(bf16x8, r);
}

// ------- fused pre-pass: feats transpose (f32->bf16) + weight permute + mask bitmap -------
__global__ __launch_bounds__(256) void k_pre(
    const float* __restrict__ fq, const float* __restrict__ fk,
    const float* __restrict__ Wq, const float* __restrict__ Wk,
    const float* __restrict__ Wf, const float* __restrict__ Wm,
    const int* __restrict__ mask,
    unsigned short* __restrict__ xqt, unsigned short* __restrict__ xkt,
    unsigned short* __restrict__ wqb, unsigned short* __restrict__ wkb,
    unsigned short* __restrict__ wfb, unsigned short* __restrict__ wmb,
    unsigned int* __restrict__ mbits)
{
  const int id = blockIdx.x;
  const int t = threadIdx.x;
  __shared__ float tile[64][65];

  if (id < 1024) {
    const int which = id >> 9;
    const int b = (id >> 8) & 1;
    const int i0 = ((id >> 5) & 7) * 64;
    const int n0 = (id & 31) * 64;
    const float* __restrict__ src = which ? fk : fq;
    unsigned short* __restrict__ dst = which ? xkt : xqt;
    const int cl = t & 63, rw = t >> 6;
    #pragma unroll
    for (int rr = 0; rr < 16; ++rr) {
      int il = rr * 4 + rw;
      tile[il][cl] = src[((size_t)b * 512 + i0 + il) * 2048 + n0 + cl];
    }
    __syncthreads();
    const int ci = (t & 31) * 2, rhalf = t >> 5;
    #pragma unroll
    for (int rr = 0; rr < 8; ++rr) {
      int nl = rr * 8 + rhalf;
      unsigned int v = (unsigned int)f2b(tile[ci][nl]) |
                       ((unsigned int)f2b(tile[ci + 1][nl]) << 16);
      *(unsigned int*)&dst[((size_t)b * 2048 + n0 + nl) * 512 + i0 + ci] = v;
    }
  } else if (id < 3072) {
    const int r = id - 1024;
    const int mat = r >> 9, cp = r & 511;
    if (mat < 3) {
      const float* W = (mat == 0) ? Wq : (mat == 1) ? Wk : Wf;
      unsigned short* O = (mat == 0) ? wqb : (mat == 1) ? wkb : wfb;
      const int orig = (cp & 63) * 8 + (cp >> 6);   // d*8+h
      for (int j = t; j < 512; j += 256)
        O[cp * 512 + j] = f2b(W[orig * 512 + j]);
    } else {
      for (int j = t; j < 512; j += 256) {
        int h = j >> 6, d = j & 63;
        wmb[cp * 512 + j] = f2b(Wm[cp * 512 + d * 8 + h]);
      }
    }
  } else {
    // mask bitmap: 2 b x 64 u32 words (bit j of word w = mask[b][w*32+j])
    if (t < 128) {
      int bb = t >> 6, wd = t & 63;
      unsigned int v = 0;
      #pragma unroll
      for (int j = 0; j < 32; ++j)
        v |= (mask[bb * 2048 + wd * 32 + j] ? 1u : 0u) << j;
      mbits[t] = v;
    }
  }
}

// ---------------- QKV projections: 128x128 NT, gl_lds 2-phase double-buffer ----------------
__global__ __launch_bounds__(256) void k_proj(
    const unsigned short* __restrict__ xqt, const unsigned short* __restrict__ xkt,
    const unsigned short* __restrict__ wqp, const unsigned short* __restrict__ wkp,
    const unsigned short* __restrict__ wfp,
    const float* __restrict__ bq, const float* __restrict__ bk, const float* __restrict__ bfv,
    unsigned short* __restrict__ Qb, unsigned short* __restrict__ Kb, unsigned short* __restrict__ VTb)
{
  const int lid = blockIdx.x;                     // 0..383
  const int orig = (lid & 7) * 48 + (lid >> 3);   // bijective (384 = 8*48)
  const int z = orig >> 6;
  const int bid = orig & 63;
  const int b = z / 3, proj = z % 3;
  const int t = threadIdx.x, w = t >> 6, l = t & 63, q = l >> 4, m16 = l & 15;
  const int wm = w >> 1, wn = w & 1;

  __shared__ __attribute__((aligned(16))) unsigned short As[2][8192];
  __shared__ __attribute__((aligned(16))) unsigned short Bs[2][8192];

  const unsigned short* A;
  const unsigned short* Bt;
  int mt, nt_;
  if (proj < 2) {
    mt = bid >> 2; nt_ = bid & 3;
    A  = (proj == 0 ? xqt : xkt) + (size_t)b * 2048 * 512 + (size_t)mt * 128 * 512;
    Bt = (proj == 0 ? wqp : wkp) + (size_t)nt_ * 128 * 512;
  } else {
    mt = bid & 3; nt_ = bid >> 2;
    A  = wfp + (size_t)mt * 128 * 512;
    Bt = xkt + (size_t)b * 2048 * 512 + (size_t)nt_ * 128 * 512;
  }

  f32x4 acc[4][4];
  const f32x4 fz = {0.f, 0.f, 0.f, 0.f};
  #pragma unroll
  for (int mf = 0; mf < 4; ++mf)
    #pragma unroll
    for (int nf = 0; nf < 4; ++nf) acc[mf][nf] = fz;

#define PROJ_STAGE(BUF, KS)                                                          \
  {                                                                                  \
    _Pragma("unroll")                                                                \
    for (int c = 0; c < 4; ++c) {                                                    \
      int slot = c * 256 + t;                                                        \
      int row = slot >> 3, j = slot & 7;                                             \
      int jj = j ^ (row & 7);                                                        \
      gl_lds16(A  + (size_t)row * 512 + (KS) * 64 + jj * 8,                          \
               (char*)As[BUF] + (c * 256 + w * 64) * 16);                            \
      gl_lds16(Bt + (size_t)row * 512 + (KS) * 64 + jj * 8,                          \
               (char*)Bs[BUF] + (c * 256 + w * 64) * 16);                            \
    }                                                                                \
  }

  PROJ_STAGE(0, 0)
  asm volatile("s_waitcnt vmcnt(0)" ::: "memory");
  __syncthreads();

  for (int ks = 0; ks < 8; ++ks) {
    const int cur = ks & 1;
    if (ks < 7) PROJ_STAGE(cur ^ 1, ks + 1)
    #pragma unroll
    for (int kk = 0; kk < 2; ++kk) {
      bf16x8 av[4], bv[4];
      #pragma unroll
      for (int mf = 0; mf < 4; ++mf) {
        int row = wm * 64 + mf * 16 + m16;
        av[mf] = *(const bf16x8*)&As[cur][row * 64 + (((kk * 4 + q) ^ (row & 7)) << 3)];
      }
      #pragma unroll
      for (int nf = 0; nf < 4; ++nf) {
        int row = wn * 64 + nf * 16 + m16;
        bv[nf] = *(const bf16x8*)&Bs[cur][row * 64 + (((kk * 4 + q) ^ (row & 7)) << 3)];
      }
      #pragma unroll
      for (int mf = 0; mf < 4; ++mf)
        #pragma unroll
        for (int nf = 0; nf < 4; ++nf)
          acc[mf][nf] = __builtin_amdgcn_mfma_f32_16x16x32_bf16(av[mf], bv[nf], acc[mf][nf], 0, 0, 0);
    }
    if (ks < 7) {
      asm volatile("s_waitcnt vmcnt(0)" ::: "memory");
      __syncthreads();
    }
  }
#undef PROJ_STAGE

  const float QSCALE = 0.18033688011112042f;   // log2(e)/8 folded into Q

  if (proj < 2) {
    const float* bias = (proj == 0) ? bq : bk;
    unsigned short* dst = (proj == 0) ? Qb : Kb;
    #pragma unroll
    for (int mf = 0; mf < 4; ++mf)
      #pragma unroll
      for (int nf = 0; nf < 4; ++nf)
        #pragma unroll
        for (int r = 0; r < 4; ++r) {
          int n  = mt * 128 + wm * 64 + mf * 16 + q * 4 + r;
          int cp = nt_ * 128 + wn * 64 + nf * 16 + m16;
          int h = cp >> 6, d = cp & 63;
          float v = acc[mf][nf][r] + bias[d * 8 + h];
          if (proj == 0) v *= QSCALE;
          dst[((size_t)(b * 8 + h) * 2048 + n) * 64 + d] = f2b(v);
        }
  } else {
    #pragma unroll
    for (int mf = 0; mf < 4; ++mf)
      #pragma unroll
      for (int nf = 0; nf < 4; ++nf)
        #pragma unroll
        for (int r = 0; r < 4; ++r) {
          int cp = mt * 128 + wm * 64 + mf * 16 + q * 4 + r;
          int n  = nt_ * 128 + wn * 64 + nf * 16 + m16;
          int h = cp >> 6, d = cp & 63;
          float v = acc[mf][nf][r] + bfv[d * 8 + h];
          VTb[((size_t)(b * 8 + h) * 64 + d) * 2048 + n] = f2b(v);
        }
  }
}

// ---- flash attention v6: wave-split KV, PINNED global->reg prefetch, no barriers/LDS in loop ----
// 512 blocks (XCD-swizzled, 2 blocks/CU = 8 waves/CU). Each wave owns KV chunks (w+4i)*32.
// Loads via asm volatile (cannot be sunk); counted vmcnt(8) keeps next chunk in flight.
// Cross-wave combine epilogue = R5-verified.
__global__ __launch_bounds__(256, 2) void k_attn6(
    const unsigned short* __restrict__ Qb, const unsigned short* __restrict__ Kb,
    const unsigned short* __restrict__ VTb, const unsigned int* __restrict__ mbits,
    unsigned short* __restrict__ OT)
{
  const int lid = blockIdx.x;                       // 0..511
  const int orig = ((lid & 7) << 6) | (lid >> 3);   // bijective (512 = 8*64)
  const int bh = orig >> 5, b = bh >> 3, h = bh & 7;
  const int nt = orig & 31;
  const int t = threadIdx.x, w = t >> 6, l = t & 63;
  const int q31 = l & 31, hi = l >> 5;

  __shared__ __attribute__((aligned(16))) char lds_all[70656];  // combine only

  const unsigned int* mrow = mbits + b * 64;

  // moving per-lane base pointers (advance per chunk; offsets via imm)
  const unsigned short* kptr = Kb + (size_t)bh * (2048 * 64) + (size_t)(w * 32 + q31) * 64 + hi * 8;
  const unsigned short* v0ptr = VTb + (size_t)bh * (64 * 2048) + (size_t)q31 * 2048 + w * 32 + hi * 8;
  const unsigned short* v1ptr = v0ptr + (size_t)32 * 2048;

  // Q fragments via pinned loads (keeps the vmcnt ledger exact)
  const unsigned short* qp0 = Qb + ((size_t)bh * 2048 + nt * 64 + q31) * 64 + hi * 8;
  const unsigned short* qp1 = qp0 + 32 * 64;
  bf16x8 qfr[2][4];
  qfr[0][0] = gload16<0>(qp0);  qfr[0][1] = gload16<32>(qp0);
  qfr[0][2] = gload16<64>(qp0); qfr[0][3] = gload16<96>(qp0);
  qfr[1][0] = gload16<0>(qp1);  qfr[1][1] = gload16<32>(qp1);
  qfr[1][2] = gload16<64>(qp1); qfr[1][3] = gload16<96>(qp1);

  f32x16 z16;
  #pragma unroll
  for (int r = 0; r < 16; ++r) z16[r] = 0.f;
  f32x16 oacc[2][2];   // [df][qf]
  oacc[0][0] = z16; oacc[0][1] = z16; oacc[1][0] = z16; oacc[1][1] = z16;
  float lpart[2] = {0.f, 0.f};

  // chunk loader: 8 pinned 16B loads (4 K + 4 V), then advance pointers
#define LOADCHUNK(KK, VV)                                                   \
  {                                                                         \
    KK[0] = gload16<0>(kptr);  KK[1] = gload16<32>(kptr);                   \
    KK[2] = gload16<64>(kptr); KK[3] = gload16<96>(kptr);                   \
    VV[0] = gload16<0>(v0ptr); VV[1] = gload16<32>(v0ptr);                  \
    VV[2] = gload16<0>(v1ptr); VV[3] = gload16<32>(v1ptr);                  \
    kptr += 8192; v0ptr += 128; v1ptr += 128;                               \
  }

#define COMPUTE(I, KK, VV)                                                            \
  {                                                                                   \
    const unsigned int mword = mrow[w + 4 * (I)];                                     \
    const unsigned int mw2 = mword >> (hi * 4);                                       \
    _Pragma("unroll")                                                                 \
    for (int qf = 0; qf < 2; ++qf) {                                                  \
      f32x16 sacc;                                                                    \
      __builtin_amdgcn_s_setprio(1);                                                  \
      sacc = __builtin_amdgcn_mfma_f32_32x32x16_bf16(KK[0], qfr[qf][0], z16, 0, 0, 0);\
      sacc = __builtin_amdgcn_mfma_f32_32x32x16_bf16(KK[1], qfr[qf][1], sacc, 0, 0, 0);\
      sacc = __builtin_amdgcn_mfma_f32_32x32x16_bf16(KK[2], qfr[qf][2], sacc, 0, 0, 0);\
      sacc = __builtin_amdgcn_mfma_f32_32x32x16_bf16(KK[3], qfr[qf][3], sacc, 0, 0, 0);\
      __builtin_amdgcn_s_setprio(0);                                                  \
      float e[16];                                                                    \
      _Pragma("unroll")                                                               \
      for (int g = 0; g < 4; ++g)                                                     \
        _Pragma("unroll")                                                             \
        for (int r2 = 0; r2 < 4; ++r2) {                                              \
          float ev = __builtin_amdgcn_exp2f(sacc[g * 4 + r2]);                        \
          e[g * 4 + r2] = ((mw2 >> (r2 + 8 * g)) & 1u) ? ev : 0.f;                    \
        }                                                                             \
      {                                                                               \
        float s0 = e[0]+e[1], s1 = e[2]+e[3], s2 = e[4]+e[5], s3 = e[6]+e[7];         \
        float s4 = e[8]+e[9], s5 = e[10]+e[11], s6 = e[12]+e[13], s7 = e[14]+e[15];   \
        lpart[qf] += ((s0+s1)+(s2+s3)) + ((s4+s5)+(s6+s7));                           \
      }                                                                               \
      unsigned int W[8];                                                              \
      _Pragma("unroll")                                                               \
      for (int j = 0; j < 8; ++j) W[j] = cvtpk(e[2*j], e[2*j+1]);                     \
      asm("v_permlane32_swap_b32 %0, %1" : "+v"(W[0]), "+v"(W[2]));                   \
      asm("v_permlane32_swap_b32 %0, %1" : "+v"(W[1]), "+v"(W[3]));                   \
      asm("v_permlane32_swap_b32 %0, %1" : "+v"(W[4]), "+v"(W[6]));                   \
      asm("v_permlane32_swap_b32 %0, %1" : "+v"(W[5]), "+v"(W[7]));                   \
      u32x4 lo4 = {W[0], W[1], W[2], W[3]};                                           \
      u32x4 hi4 = {W[4], W[5], W[6], W[7]};                                           \
      bf16x8 pb0 = __builtin_bit_cast(bf16x8, lo4);                                   \
      bf16x8 pb1 = __builtin_bit_cast(bf16x8, hi4);                                   \
      __builtin_amdgcn_s_setprio(1);                                                  \
      oacc[0][qf] = __builtin_amdgcn_mfma_f32_32x32x16_bf16(VV[0], pb0, oacc[0][qf], 0, 0, 0);\
      oacc[0][qf] = __builtin_amdgcn_mfma_f32_32x32x16_bf16(VV[1], pb1, oacc[0][qf], 0, 0, 0);\
      oacc[1][qf] = __builtin_amdgcn_mfma_f32_32x32x16_bf16(VV[2], pb0, oacc[1][qf], 0, 0, 0);\
      oacc[1][qf] = __builtin_amdgcn_mfma_f32_32x32x16_bf16(VV[3], pb1, oacc[1][qf], 0, 0, 0);\
      __builtin_amdgcn_s_setprio(0);                                                  \
    }                                                                                 \
  }

  bf16x8 kA[4], vA[4], kB[4], vB[4];
  LOADCHUNK(kA, vA)                         // outstanding: Q(8) + A(8)
  for (int ii = 0; ii < 8; ++ii) {
    LOADCHUNK(kB, vB)                       // + B(8)
    asm volatile("s_waitcnt vmcnt(8)" ::: "memory");   // Q + A complete, B in flight
    __builtin_amdgcn_sched_barrier(0);
    COMPUTE(2 * ii, kA, vA)
    if (ii < 7) {
      LOADCHUNK(kA, vA)
      asm volatile("s_waitcnt vmcnt(8)" ::: "memory"); // B complete, next A in flight
    } else {
      asm volatile("s_waitcnt vmcnt(0)" ::: "memory");
    }
    __builtin_amdgcn_sched_barrier(0);
    COMPUTE(2 * ii + 1, kB, vB)
  }
#undef LOADCHUNK
#undef COMPUTE

  // ---- cross-wave combine: O = sum_w O_w, l = sum_w l_w (verified R5) ----
  float* pc = (float*)lds_all;                 // [w][q 64][68 floats] (padded stride)
  float* ls = (float*)(lds_all + 69632);       // [w][q 64]
  #pragma unroll
  for (int qf = 0; qf < 2; ++qf) {
    float lfull = lpart[qf] + __shfl_xor(lpart[qf], 32);
    int qq = qf * 32 + q31;
    if (hi == 0) ls[w * 64 + qq] = lfull;
    #pragma unroll
    for (int df = 0; df < 2; ++df)
      #pragma unroll
      for (int g = 0; g < 4; ++g) {
        f32x4 v4 = {oacc[df][qf][g*4+0], oacc[df][qf][g*4+1],
                    oacc[df][qf][g*4+2], oacc[df][qf][g*4+3]};
        *(f32x4*)&pc[w * 4352 + qq * 68 + df * 32 + g * 8 + hi * 4] = v4;
      }
  }
  __syncthreads();
  {
    const int q = t >> 2, ds = (t & 3) * 16;
    float lsumv = ls[q] + ls[64 + q] + ls[128 + q] + ls[192 + q];
    f32x4 o4[4];
    #pragma unroll
    for (int j = 0; j < 4; ++j) o4[j] = *(const f32x4*)&pc[q * 68 + ds + j * 4];
    #pragma unroll
    for (int ww = 1; ww < 4; ++ww)
      #pragma unroll
      for (int j = 0; j < 4; ++j) {
        f32x4 p4 = *(const f32x4*)&pc[ww * 4352 + q * 68 + ds + j * 4];
        o4[j] += p4;
      }
    float rinv = __builtin_amdgcn_rcpf(lsumv);
    unsigned int pk[8];
    #pragma unroll
    for (int j = 0; j < 4; ++j) {
      pk[2*j]   = cvtpk(o4[j][0] * rinv, o4[j][1] * rinv);
      pk[2*j+1] = cvtpk(o4[j][2] * rinv, o4[j][3] * rinv);
    }
    unsigned short* dst = &OT[((size_t)b * 2048 + nt * 64 + q) * 512 + h * 64 + ds];
    u32x4 s0 = {pk[0], pk[1], pk[2], pk[3]};
    u32x4 s1 = {pk[4], pk[5], pk[6], pk[7]};
    *(u32x4*)dst = s0;
    *(u32x4*)(dst + 8) = s1;
  }
}

// --------- fused: final projection + bias + f32 residual + channel-LN + transposed store ---------
__global__ __launch_bounds__(256) void k_out(
    const unsigned short* __restrict__ OT, const unsigned short* __restrict__ wmw,
    const float* __restrict__ bm, const float* __restrict__ fq,
    const float* __restrict__ g, const float* __restrict__ be,
    float* __restrict__ out)
{
  const int b = blockIdx.y;
  const int n0 = blockIdx.x * 32;
  const int t = threadIdx.x, w = t >> 6, l = t & 63, q = l >> 4, m16 = l & 15;

  __shared__ __attribute__((aligned(16))) unsigned short As[2][2048];    // 2 x 4 KB
  __shared__ __attribute__((aligned(16))) unsigned short Bs[2][32768];   // 2 x 64 KB
  __shared__ float ssum[4][32], ssq[4][32];

  f32x4 acc[2][8];
  const f32x4 fz = {0.f, 0.f, 0.f, 0.f};
  #pragma unroll
  for (int mf = 0; mf < 2; ++mf)
    #pragma unroll
    for (int nf = 0; nf < 8; ++nf) acc[mf][nf] = fz;

  const unsigned short* Abase = OT + ((size_t)b * 2048 + n0) * 512;
  const unsigned short* Bbase = wmw;

#define OUT_STAGE(BUF, KS)                                                          \
  {                                                                                 \
    { int row = t >> 3, j = t & 7;                                                  \
      gl_lds16(Abase + (size_t)row * 512 + (KS) * 64 + ((j ^ (row & 7)) * 8),       \
               (char*)As[BUF] + w * 1024); }                                        \
    _Pragma("unroll")                                                               \
    for (int c = 0; c < 16; ++c) {                                                  \
      int slot = c * 256 + t;                                                       \
      int row = slot >> 3, j = slot & 7;                                            \
      gl_lds16(Bbase + (size_t)row * 512 + (KS) * 64 + ((j ^ (row & 7)) * 8),       \
               (char*)Bs[BUF] + (c * 256 + w * 64) * 16);                           \
    }                                                                               \
  }

  OUT_STAGE(0, 0)
  asm volatile("s_waitcnt vmcnt(0)" ::: "memory");
  __syncthreads();

  for (int ks = 0; ks < 8; ++ks) {
    const int cur = ks & 1;
    if (ks < 7) OUT_STAGE(cur ^ 1, ks + 1)
    #pragma unroll
    for (int kk = 0; kk < 2; ++kk) {
      bf16x8 av[2];
      #pragma unroll
      for (int mf = 0; mf < 2; ++mf) {
        int row = mf * 16 + m16;
        av[mf] = *(const bf16x8*)((const char*)As[cur] + row * 128 + (((kk * 4 + q) ^ (row & 7)) * 16));
      }
      #pragma unroll
      for (int nf = 0; nf < 8; ++nf) {
        int row = w * 128 + nf * 16 + m16;
        bf16x8 bv = *(const bf16x8*)((const char*)Bs[cur] + row * 128 + (((kk * 4 + q) ^ (row & 7)) * 16));
        acc[0][nf] = __builtin_amdgcn_mfma_f32_16x16x32_bf16(av[0], bv, acc[0][nf], 0, 0, 0);
        acc[1][nf] = __builtin_amdgcn_mfma_f32_16x16x32_bf16(av[1], bv, acc[1][nf], 0, 0, 0);
      }
    }
    if (ks < 7) {
      asm volatile("s_waitcnt vmcnt(0)" ::: "memory");
      __syncthreads();
    }
  }
#undef OUT_STAGE

  float gv[8], bev[8], bmv[8];
  #pragma unroll
  for (int nf = 0; nf < 8; ++nf) {
    int c = w * 128 + nf * 16 + m16;
    gv[nf] = g[c]; bev[nf] = be[c]; bmv[nf] = bm[c];
  }
  #pragma unroll
  for (int mf = 0; mf < 2; ++mf)
    #pragma unroll
    for (int nf = 0; nf < 8; ++nf) {
      int c = w * 128 + nf * 16 + m16;
      f32x4 res = *(const f32x4*)&fq[((size_t)b * 512 + c) * 2048 + n0 + mf * 16 + q * 4];
      #pragma unroll
      for (int r = 0; r < 4; ++r)
        acc[mf][nf][r] += bmv[nf] + res[r];
    }
  #pragma unroll
  for (int mf = 0; mf < 2; ++mf)
    #pragma unroll
    for (int r = 0; r < 4; ++r) {
      float ps = 0.f, pss = 0.f;
      #pragma unroll
      for (int nf = 0; nf < 8; ++nf) {
        float v = acc[mf][nf][r];
        ps += v; pss += v * v;
      }
      ps += __shfl_xor(ps, 1); pss += __shfl_xor(pss, 1);
      ps += __shfl_xor(ps, 2); pss += __shfl_xor(pss, 2);
      ps += __shfl_xor(ps, 4); pss += __shfl_xor(pss, 4);
      ps += __shfl_xor(ps, 8); pss += __shfl_xor(pss, 8);
      if (m16 == 0) {
        ssum[w][mf * 16 + q * 4 + r] = ps;
        ssq[w][mf * 16 + q * 4 + r] = pss;
      }
    }
  __syncthreads();
  #pragma unroll
  for (int mf = 0; mf < 2; ++mf)
    #pragma unroll
    for (int r = 0; r < 4; ++r) {
      int nl = mf * 16 + q * 4 + r;
      float S  = ssum[0][nl] + ssum[1][nl] + ssum[2][nl] + ssum[3][nl];
      float SS = ssq[0][nl] + ssq[1][nl] + ssq[2][nl] + ssq[3][nl];
      float mu = S * (1.f / 512.f);
      float var = SS * (1.f / 512.f) - mu * mu;
      float rstd = rsqrtf(var + 1e-5f);
      #pragma unroll
      for (int nf = 0; nf < 8; ++nf)
        acc[mf][nf][r] = (acc[mf][nf][r] - mu) * rstd * gv[nf] + bev[nf];
    }
  #pragma unroll
  for (int mf = 0; mf < 2; ++mf)
    #pragma unroll
    for (int nf = 0; nf < 8; ++nf) {
      int c = w * 128 + nf * 16 + m16;
      *(f32x4*)&out[((size_t)b * 512 + c) * 2048 + n0 + mf * 16 + q * 4] = acc[mf][nf];
    }
}

// ---------------- launcher ----------------
extern "C" void kernel_launch(void* const* d_in, const int* in_sizes, int n_in,
                              void* d_out, int out_size, void* d_ws, size_t ws_size,
                              hipStream_t stream) {
  const float* fq  = (const float*)d_in[0];
  const float* fk  = (const float*)d_in[1];
  const int*   msk = (const int*)d_in[2];
  const float* Wq  = (const float*)d_in[3];
  const float* bq  = (const float*)d_in[4];
  const float* Wk  = (const float*)d_in[5];
  const float* bk  = (const float*)d_in[6];
  const float* Wf  = (const float*)d_in[7];
  const float* bfv = (const float*)d_in[8];
  const float* Wm  = (const float*)d_in[9];
  const float* bm  = (const float*)d_in[10];
  const float* lng = (const float*)d_in[11];
  const float* lnb = (const float*)d_in[12];
  float* out = (float*)d_out;

  char* ws = (char*)d_ws;
  const size_t MB = 1024 * 1024;
  unsigned short* xqt = (unsigned short*)(ws + 0 * MB);        // 4 MB  [b][n][512] bf16
  unsigned short* xkt = (unsigned short*)(ws + 4 * MB);        // 4 MB
  unsigned short* wqb = (unsigned short*)(ws + 8 * MB);        // 512 KB
  unsigned short* wkb = (unsigned short*)(ws + 8 * MB + 512 * 1024);
  unsigned short* wfb = (unsigned short*)(ws + 9 * MB);
  unsigned short* wmb = (unsigned short*)(ws + 9 * MB + 512 * 1024);
  unsigned short* Qb  = (unsigned short*)(ws + 10 * MB);       // 4 MB  [bh][n][64]
  unsigned short* Kb  = (unsigned short*)(ws + 14 * MB);       // 4 MB  [bh][m][64]
  unsigned short* VTb = (unsigned short*)(ws + 18 * MB);       // 4 MB  [bh][64][m]
  unsigned short* OTb = (unsigned short*)(ws + 22 * MB);       // 4 MB  [b][n][512]
  unsigned int*   mbits = (unsigned int*)(ws + 26 * MB);       // 512 B

  hipLaunchKernelGGL(k_pre, dim3(3073), dim3(256), 0, stream,
                     fq, fk, Wq, Wk, Wf, Wm, msk, xqt, xkt, wqb, wkb, wfb, wmb, mbits);
  hipLaunchKernelGGL(k_proj, dim3(384), dim3(256), 0, stream,
                     xqt, xkt, wqb, wkb, wfb, bq, bk, bfv, Qb, Kb, VTb);
  hipLaunchKernelGGL(k_attn6, dim3(512), dim3(256), 0, stream, Qb, Kb, VTb, mbits, OTb);
  hipLaunchKernelGGL(k_out, dim3(64, 2), dim3(256), 0, stream,
                     OTb, wmb, bm, fq, lng, lnb, out);
}

// Round 10
// 68.336 us; speedup vs baseline: 1.3135x; 1.1983x over previous
//
#include <hip/hip_runtime.h>
#include <hip/hip_bf16.h>

// B=2, D=512, N=2048, H=8, head=64.

using bf16x8 = __attribute__((ext_vector_type(8))) __bf16;
using f32x4  = __attribute__((ext_vector_type(4))) float;
using f32x16 = __attribute__((ext_vector_type(16))) float;
using us8    = __attribute__((ext_vector_type(8))) unsigned short;
using u32x4  = __attribute__((ext_vector_type(4))) unsigned int;

__device__ __forceinline__ unsigned short f2b(float f) {
  unsigned int u = __builtin_bit_cast(unsigned int, f);
  u += 0x7fffu + ((u >> 16) & 1u);
  return (unsigned short)(u >> 16);
}
__device__ __forceinline__ float b2f(unsigned short s) {
  unsigned int u = ((unsigned int)s) << 16;
  return __builtin_bit_cast(float, u);
}
__device__ __forceinline__ unsigned int cvtpk(float lo, float hi) {
  unsigned int w;
  asm("v_cvt_pk_bf16_f32 %0, %1, %2" : "=v"(w) : "v"(lo), "v"(hi));
  return w;
}
__device__ __forceinline__ void gl_lds16(const void* g, void* l) {
  __builtin_amdgcn_global_load_lds((const __attribute__((address_space(1))) void*)g,
                                   (__attribute__((address_space(3))) void*)l, 16, 0, 0);
}

// ------- fused pre-pass: feats transpose (f32->bf16) + weight permute + mask bias -------
__global__ __launch_bounds__(256) void k_pre(
    const float* __restrict__ fq, const float* __restrict__ fk,
    const float* __restrict__ Wq, const float* __restrict__ Wk,
    const float* __restrict__ Wf, const float* __restrict__ Wm,
    const int* __restrict__ mask,
    unsigned short* __restrict__ xqt, unsigned short* __restrict__ xkt,
    unsigned short* __restrict__ wqb, unsigned short* __restrict__ wkb,
    unsigned short* __restrict__ wfb, unsigned short* __restrict__ wmb,
    float* __restrict__ biasf)
{
  const int id = blockIdx.x;
  const int t = threadIdx.x;
  __shared__ float tile[64][65];

  if (id < 1024) {
    const int which = id >> 9;
    const int b = (id >> 8) & 1;
    const int i0 = ((id >> 5) & 7) * 64;
    const int n0 = (id & 31) * 64;
    const float* __restrict__ src = which ? fk : fq;
    unsigned short* __restrict__ dst = which ? xkt : xqt;
    const int cl = t & 63, rw = t >> 6;
    #pragma unroll
    for (int rr = 0; rr < 16; ++rr) {
      int il = rr * 4 + rw;
      tile[il][cl] = src[((size_t)b * 512 + i0 + il) * 2048 + n0 + cl];
    }
    __syncthreads();
    const int ci = (t & 31) * 2, rhalf = t >> 5;
    #pragma unroll
    for (int rr = 0; rr < 8; ++rr) {
      int nl = rr * 8 + rhalf;
      unsigned int v = (unsigned int)f2b(tile[ci][nl]) |
                       ((unsigned int)f2b(tile[ci + 1][nl]) << 16);
      *(unsigned int*)&dst[((size_t)b * 2048 + n0 + nl) * 512 + i0 + ci] = v;
    }
  } else if (id < 3072) {
    const int r = id - 1024;
    const int mat = r >> 9, cp = r & 511;
    if (mat < 3) {
      const float* W = (mat == 0) ? Wq : (mat == 1) ? Wk : Wf;
      unsigned short* O = (mat == 0) ? wqb : (mat == 1) ? wkb : wfb;
      const int orig = (cp & 63) * 8 + (cp >> 6);   // d*8+h
      for (int j = t; j < 512; j += 256)
        O[cp * 512 + j] = f2b(W[orig * 512 + j]);
    } else {
      for (int j = t; j < 512; j += 256) {
        int h = j >> 6, d = j & 63;
        wmb[cp * 512 + j] = f2b(Wm[cp * 512 + d * 8 + h]);
      }
    }
  } else {
    const int r = id - 3072;
    if (r < 16) {
      int i = r * 256 + t;
      biasf[i] = mask[i] ? 0.f : -100000.f;
    }
  }
}

// -------- QKV projections: 128x64 NT tiles, 768 blocks (3/CU exact), gl_lds 2-phase --------
__global__ __launch_bounds__(256) void k_proj(
    const unsigned short* __restrict__ xqt, const unsigned short* __restrict__ xkt,
    const unsigned short* __restrict__ wqp, const unsigned short* __restrict__ wkp,
    const unsigned short* __restrict__ wfp,
    const float* __restrict__ bq, const float* __restrict__ bk, const float* __restrict__ bfv,
    unsigned short* __restrict__ Qb, unsigned short* __restrict__ Kb, unsigned short* __restrict__ VTb)
{
  const int lid = blockIdx.x;                     // 0..767
  const int orig = (lid & 7) * 96 + (lid >> 3);   // bijective (768 = 8*96)
  const int z = orig / 128;                       // 0..5
  const int bid = orig % 128;
  const int b = z / 3, proj = z % 3;
  const int t = threadIdx.x, w = t >> 6, l = t & 63, q = l >> 4, m16 = l & 15;
  const int wm = w >> 1, wn = w & 1;              // 2x2 waves; wave tile 64x32

  __shared__ __attribute__((aligned(16))) unsigned short As[2][8192];   // 128x64
  __shared__ __attribute__((aligned(16))) unsigned short Bs[2][4096];   // 64x64

  const unsigned short* A;
  const unsigned short* Bt;
  int mt, nt_;
  if (proj < 2) {
    mt = bid >> 3; nt_ = bid & 7;                 // 16 x 8
    A  = (proj == 0 ? xqt : xkt) + (size_t)b * 2048 * 512 + (size_t)mt * 128 * 512;
    Bt = (proj == 0 ? wqp : wkp) + (size_t)nt_ * 64 * 512;
  } else {
    mt = bid & 3; nt_ = bid >> 2;                 // 4 x 32
    A  = wfp + (size_t)mt * 128 * 512;
    Bt = xkt + (size_t)b * 2048 * 512 + (size_t)nt_ * 64 * 512;
  }

  f32x4 acc[4][2];
  const f32x4 fz = {0.f, 0.f, 0.f, 0.f};
  #pragma unroll
  for (int mf = 0; mf < 4; ++mf)
    #pragma unroll
    for (int nf = 0; nf < 2; ++nf) acc[mf][nf] = fz;

#define PROJ_STAGE(BUF, KS)                                                          \
  {                                                                                  \
    _Pragma("unroll")                                                                \
    for (int c = 0; c < 4; ++c) {                                                    \
      int slot = c * 256 + t;                                                        \
      int row = slot >> 3, j = slot & 7;                                             \
      gl_lds16(A + (size_t)row * 512 + (KS) * 64 + ((j ^ (row & 7)) * 8),            \
               (char*)As[BUF] + (c * 256 + w * 64) * 16);                            \
    }                                                                                \
    _Pragma("unroll")                                                                \
    for (int c = 0; c < 2; ++c) {                                                    \
      int slot = c * 256 + t;                                                        \
      int row = slot >> 3, j = slot & 7;                                             \
      gl_lds16(Bt + (size_t)row * 512 + (KS) * 64 + ((j ^ (row & 7)) * 8),           \
               (char*)Bs[BUF] + (c * 256 + w * 64) * 16);                            \
    }                                                                                \
  }

  PROJ_STAGE(0, 0)
  asm volatile("s_waitcnt vmcnt(0)" ::: "memory");
  __syncthreads();

  for (int ks = 0; ks < 8; ++ks) {
    const int cur = ks & 1;
    if (ks < 7) PROJ_STAGE(cur ^ 1, ks + 1)
    #pragma unroll
    for (int kk = 0; kk < 2; ++kk) {
      bf16x8 av[4], bv[2];
      #pragma unroll
      for (int mf = 0; mf < 4; ++mf) {
        int row = wm * 64 + mf * 16 + m16;
        av[mf] = *(const bf16x8*)&As[cur][row * 64 + (((kk * 4 + q) ^ (row & 7)) << 3)];
      }
      #pragma unroll
      for (int nf = 0; nf < 2; ++nf) {
        int row = wn * 32 + nf * 16 + m16;
        bv[nf] = *(const bf16x8*)&Bs[cur][row * 64 + (((kk * 4 + q) ^ (row & 7)) << 3)];
      }
      #pragma unroll
      for (int mf = 0; mf < 4; ++mf)
        #pragma unroll
        for (int nf = 0; nf < 2; ++nf)
          acc[mf][nf] = __builtin_amdgcn_mfma_f32_16x16x32_bf16(av[mf], bv[nf], acc[mf][nf], 0, 0, 0);
    }
    if (ks < 7) {
      asm volatile("s_waitcnt vmcnt(0)" ::: "memory");
      __syncthreads();
    }
  }
#undef PROJ_STAGE

  const float QSCALE = 0.18033688011112042f;   // log2(e)/8 folded into Q

  if (proj < 2) {
    const float* bias = (proj == 0) ? bq : bk;
    unsigned short* dst = (proj == 0) ? Qb : Kb;
    #pragma unroll
    for (int mf = 0; mf < 4; ++mf)
      #pragma unroll
      for (int nf = 0; nf < 2; ++nf)
        #pragma unroll
        for (int r = 0; r < 4; ++r) {
          int n  = mt * 128 + wm * 64 + mf * 16 + q * 4 + r;
          int cp = nt_ * 64 + wn * 32 + nf * 16 + m16;
          int h = cp >> 6, d = cp & 63;
          float v = acc[mf][nf][r] + bias[d * 8 + h];
          if (proj == 0) v *= QSCALE;
          dst[((size_t)(b * 8 + h) * 2048 + n) * 64 + d] = f2b(v);
        }
  } else {
    #pragma unroll
    for (int mf = 0; mf < 4; ++mf)
      #pragma unroll
      for (int nf = 0; nf < 2; ++nf)
        #pragma unroll
        for (int r = 0; r < 4; ++r) {
          int cp = mt * 128 + wm * 64 + mf * 16 + q * 4 + r;
          int n  = nt_ * 64 + wn * 32 + nf * 16 + m16;
          int h = cp >> 6, d = cp & 63;
          float v = acc[mf][nf][r] + bfv[d * 8 + h];
          VTb[((size_t)(b * 8 + h) * 64 + d) * 2048 + n] = f2b(v);
        }
  }
}

// ---------------- flash attention (R5-verified): wave-split KV + LDS cross-wave combine ----------------
__global__ __launch_bounds__(256, 2) void k_attn2(
    const unsigned short* __restrict__ Qb, const unsigned short* __restrict__ Kb,
    const unsigned short* __restrict__ VTb, const float* __restrict__ biasf,
    unsigned short* __restrict__ OT)
{
  const int lid = blockIdx.x;                       // 0..511
  const int orig = ((lid & 7) << 6) | (lid >> 3);   // bijective (512 = 8*64)
  const int bh = orig >> 5, b = bh >> 3, h = bh & 7;
  const int nt = orig & 31;
  const int t = threadIdx.x, w = t >> 6, l = t & 63;
  const int q31 = l & 31, hi = l >> 5;

  __shared__ __attribute__((aligned(16))) char lds_all[70656];
  char* kbuf = lds_all + w * 8192;            // 2 x 4KB K double-buffer (per wave)
  char* vbuf = lds_all + 32768 + w * 8192;    // 2 x 4KB V double-buffer (per wave)

  const unsigned short* Kp = Kb + (size_t)bh * (2048 * 64);
  const unsigned short* Vp = VTb + (size_t)bh * (64 * 2048);
  const float* brow = biasf + b * 2048;

  bf16x8 qfr[2][4];
  {
    const unsigned short* Qp = Qb + ((size_t)bh * 2048 + nt * 64) * 64;
    #pragma unroll
    for (int qf = 0; qf < 2; ++qf)
      #pragma unroll
      for (int tq = 0; tq < 4; ++tq)
        qfr[qf][tq] = *(const bf16x8*)&Qp[(qf * 32 + q31) * 64 + tq * 16 + hi * 8];
  }

  f32x16 z16;
  #pragma unroll
  for (int r = 0; r < 16; ++r) z16[r] = 0.f;

  f32x16 oacc[2][2];   // [df][qf]
  #pragma unroll
  for (int i = 0; i < 2; ++i)
    #pragma unroll
    for (int j2 = 0; j2 < 2; ++j2) oacc[i][j2] = z16;
  float lpart[2] = {0.f, 0.f};

  const int kr3 = l >> 3, ks3 = l & 7;
  const int vr4 = l >> 2, vs2 = l & 3;

  {
    int kv0 = w * 32;
    #pragma unroll
    for (int j = 0; j < 4; ++j)
      gl_lds16(Kp + (size_t)(kv0 + j * 8 + kr3) * 64 + (ks3 ^ kr3) * 8, kbuf + j * 1024);
    #pragma unroll
    for (int j = 0; j < 4; ++j) {
      int d = j * 16 + vr4;
      gl_lds16(Vp + (size_t)d * 2048 + kv0 + (vs2 ^ (d & 3)) * 8, vbuf + j * 1024);
    }
  }

  #pragma unroll 2
  for (int i = 0; i < 16; ++i) {
    const int bufi = i & 1;
    const int kv0 = (w + 4 * i) * 32;

    float4 bias[4];
    #pragma unroll
    for (int g = 0; g < 4; ++g)
      bias[g] = *(const float4*)&brow[kv0 + g * 8 + hi * 4];

    if (i < 15) {
      const int kvn = (w + 4 * (i + 1)) * 32;
      char* kb2 = kbuf + (bufi ^ 1) * 4096;
      char* vb2 = vbuf + (bufi ^ 1) * 4096;
      #pragma unroll
      for (int j = 0; j < 4; ++j)
        gl_lds16(Kp + (size_t)(kvn + j * 8 + kr3) * 64 + (ks3 ^ kr3) * 8, kb2 + j * 1024);
      #pragma unroll
      for (int j = 0; j < 4; ++j) {
        int d = j * 16 + vr4;
        gl_lds16(Vp + (size_t)d * 2048 + kvn + (vs2 ^ (d & 3)) * 8, vb2 + j * 1024);
      }
      asm volatile("s_waitcnt vmcnt(8)" ::: "memory");
    } else {
      asm volatile("s_waitcnt vmcnt(0)" ::: "memory");
    }
    __builtin_amdgcn_sched_barrier(0);

    const char* kb = kbuf + bufi * 4096;
    const char* vb = vbuf + bufi * 4096;

    bf16x8 ak[4];
    #pragma unroll
    for (int tq = 0; tq < 4; ++tq)
      ak[tq] = *(const bf16x8*)(kb + q31 * 128 + ((((tq << 1) | hi) ^ (q31 & 7)) * 16));

    f32x16 sacc[2];
    __builtin_amdgcn_s_setprio(1);
    sacc[0] = __builtin_amdgcn_mfma_f32_32x32x16_bf16(ak[0], qfr[0][0], z16, 0, 0, 0);
    sacc[1] = __builtin_amdgcn_mfma_f32_32x32x16_bf16(ak[0], qfr[1][0], z16, 0, 0, 0);
    #pragma unroll
    for (int tq = 1; tq < 4; ++tq) {
      sacc[0] = __builtin_amdgcn_mfma_f32_32x32x16_bf16(ak[tq], qfr[0][tq], sacc[0], 0, 0, 0);
      sacc[1] = __builtin_amdgcn_mfma_f32_32x32x16_bf16(ak[tq], qfr[1][tq], sacc[1], 0, 0, 0);
    }
    __builtin_amdgcn_s_setprio(0);

    bf16x8 av[2][2];
    #pragma unroll
    for (int df = 0; df < 2; ++df)
      #pragma unroll
      for (int tt = 0; tt < 2; ++tt)
        av[df][tt] = *(const bf16x8*)(vb + (df * 32 + q31) * 64 + ((((tt << 1) | hi) ^ (q31 & 3)) * 16));

    #pragma unroll
    for (int qf = 0; qf < 2; ++qf) {
      float e[16];
      #pragma unroll
      for (int g = 0; g < 4; ++g) {
        e[g*4+0] = __builtin_amdgcn_exp2f(sacc[qf][g*4+0] + bias[g].x);
        e[g*4+1] = __builtin_amdgcn_exp2f(sacc[qf][g*4+1] + bias[g].y);
        e[g*4+2] = __builtin_amdgcn_exp2f(sacc[qf][g*4+2] + bias[g].z);
        e[g*4+3] = __builtin_amdgcn_exp2f(sacc[qf][g*4+3] + bias[g].w);
      }
      float s0 = 0.f;
      #pragma unroll
      for (int r = 0; r < 16; ++r) s0 += e[r];
      lpart[qf] += s0;

      unsigned int W[8];
      #pragma unroll
      for (int j = 0; j < 8; ++j) W[j] = cvtpk(e[2*j], e[2*j+1]);
      asm("v_permlane32_swap_b32 %0, %1" : "+v"(W[0]), "+v"(W[2]));
      asm("v_permlane32_swap_b32 %0, %1" : "+v"(W[1]), "+v"(W[3]));
      asm("v_permlane32_swap_b32 %0, %1" : "+v"(W[4]), "+v"(W[6]));
      asm("v_permlane32_swap_b32 %0, %1" : "+v"(W[5]), "+v"(W[7]));
      u32x4 lo4 = {W[0], W[1], W[2], W[3]};
      u32x4 hi4 = {W[4], W[5], W[6], W[7]};
      bf16x8 pb0 = __builtin_bit_cast(bf16x8, lo4);
      bf16x8 pb1 = __builtin_bit_cast(bf16x8, hi4);

      __builtin_amdgcn_s_setprio(1);
      oacc[0][qf] = __builtin_amdgcn_mfma_f32_32x32x16_bf16(av[0][0], pb0, oacc[0][qf], 0, 0, 0);
      oacc[0][qf] = __builtin_amdgcn_mfma_f32_32x32x16_bf16(av[0][1], pb1, oacc[0][qf], 0, 0, 0);
      oacc[1][qf] = __builtin_amdgcn_mfma_f32_32x32x16_bf16(av[1][0], pb0, oacc[1][qf], 0, 0, 0);
      oacc[1][qf] = __builtin_amdgcn_mfma_f32_32x32x16_bf16(av[1][1], pb1, oacc[1][qf], 0, 0, 0);
      __builtin_amdgcn_s_setprio(0);
    }
  }

  // ---- cross-wave combine: O = sum_w O_w, l = sum_w l_w ----
  float* pc = (float*)lds_all;                 // [w][q 64][68 floats]
  float* ls = (float*)(lds_all + 69632);       // [w][q 64]
  __syncthreads();
  #pragma unroll
  for (int qf = 0; qf < 2; ++qf) {
    float lfull = lpart[qf] + __shfl_xor(lpart[qf], 32);
    int qq = qf * 32 + q31;
    if (hi == 0) ls[w * 64 + qq] = lfull;
    #pragma unroll
    for (int df = 0; df < 2; ++df)
      #pragma unroll
      for (int g = 0; g < 4; ++g) {
        f32x4 v4 = {oacc[df][qf][g*4+0], oacc[df][qf][g*4+1],
                    oacc[df][qf][g*4+2], oacc[df][qf][g*4+3]};
        *(f32x4*)&pc[w * 4352 + qq * 68 + df * 32 + g * 8 + hi * 4] = v4;
      }
  }
  __syncthreads();
  {
    const int q = t >> 2, ds = (t & 3) * 16;
    float lsumv = ls[q] + ls[64 + q] + ls[128 + q] + ls[192 + q];
    f32x4 o4[4];
    #pragma unroll
    for (int j = 0; j < 4; ++j) o4[j] = *(const f32x4*)&pc[q * 68 + ds + j * 4];
    #pragma unroll
    for (int ww = 1; ww < 4; ++ww)
      #pragma unroll
      for (int j = 0; j < 4; ++j) {
        f32x4 p4 = *(const f32x4*)&pc[ww * 4352 + q * 68 + ds + j * 4];
        o4[j] += p4;
      }
    float rinv = __builtin_amdgcn_rcpf(lsumv);
    unsigned int pk[8];
    #pragma unroll
    for (int j = 0; j < 4; ++j) {
      pk[2*j]   = cvtpk(o4[j][0] * rinv, o4[j][1] * rinv);
      pk[2*j+1] = cvtpk(o4[j][2] * rinv, o4[j][3] * rinv);
    }
    unsigned short* dst = &OT[((size_t)b * 2048 + nt * 64 + q) * 512 + h * 64 + ds];
    u32x4 s0 = {pk[0], pk[1], pk[2], pk[3]};
    u32x4 s1 = {pk[4], pk[5], pk[6], pk[7]};
    *(u32x4*)dst = s0;
    *(u32x4*)(dst + 8) = s1;
  }
}

// --------- fused: final projection + residual + channel-LN; 16-row tiles -> 256 blocks ---------
__global__ __launch_bounds__(256) void k_out(
    const unsigned short* __restrict__ OT, const unsigned short* __restrict__ wmw,
    const float* __restrict__ bm, const float* __restrict__ fq,
    const float* __restrict__ g, const float* __restrict__ be,
    float* __restrict__ out)
{
  const int b = blockIdx.y;
  const int n0 = blockIdx.x * 16;
  const int t = threadIdx.x, w = t >> 6, l = t & 63, q = l >> 4, m16 = l & 15;

  __shared__ __attribute__((aligned(16))) unsigned short As[2][1024];    // 2 x 2 KB (16x64)
  __shared__ __attribute__((aligned(16))) unsigned short Bs[2][32768];   // 2 x 64 KB (512x64)
  __shared__ float ssum[4][16], ssq[4][16];

  f32x4 acc[8];
  const f32x4 fz = {0.f, 0.f, 0.f, 0.f};
  #pragma unroll
  for (int nf = 0; nf < 8; ++nf) acc[nf] = fz;

  const unsigned short* Abase = OT + ((size_t)b * 2048 + n0) * 512;
  const unsigned short* Bbase = wmw;

#define OUT_STAGE(BUF, KS)                                                          \
  {                                                                                 \
    if (t < 128) {                                                                  \
      int row = t >> 3, j = t & 7;                                                  \
      gl_lds16(Abase + (size_t)row * 512 + (KS) * 64 + ((j ^ (row & 7)) * 8),       \
               (char*)As[BUF] + w * 1024);                                          \
    }                                                                               \
    _Pragma("unroll")                                                               \
    for (int c = 0; c < 16; ++c) {                                                  \
      int slot = c * 256 + t;                                                       \
      int row = slot >> 3, j = slot & 7;                                            \
      gl_lds16(Bbase + (size_t)row * 512 + (KS) * 64 + ((j ^ (row & 7)) * 8),       \
               (char*)Bs[BUF] + (c * 256 + w * 64) * 16);                           \
    }                                                                               \
  }

  OUT_STAGE(0, 0)
  asm volatile("s_waitcnt vmcnt(0)" ::: "memory");
  __syncthreads();

  for (int ks = 0; ks < 8; ++ks) {
    const int cur = ks & 1;
    if (ks < 7) OUT_STAGE(cur ^ 1, ks + 1)
    #pragma unroll
    for (int kk = 0; kk < 2; ++kk) {
      bf16x8 av;
      {
        int row = m16;
        av = *(const bf16x8*)((const char*)As[cur] + row * 128 + (((kk * 4 + q) ^ (row & 7)) * 16));
      }
      #pragma unroll
      for (int nf = 0; nf < 8; ++nf) {
        int row = w * 128 + nf * 16 + m16;
        bf16x8 bv = *(const bf16x8*)((const char*)Bs[cur] + row * 128 + (((kk * 4 + q) ^ (row & 7)) * 16));
        acc[nf] = __builtin_amdgcn_mfma_f32_16x16x32_bf16(av, bv, acc[nf], 0, 0, 0);
      }
    }
    if (ks < 7) {
      asm volatile("s_waitcnt vmcnt(0)" ::: "memory");
      __syncthreads();
    }
  }
#undef OUT_STAGE

  float gv[8], bev[8], bmv[8];
  #pragma unroll
  for (int nf = 0; nf < 8; ++nf) {
    int c = w * 128 + nf * 16 + m16;
    gv[nf] = g[c]; bev[nf] = be[c]; bmv[nf] = bm[c];
  }
  #pragma unroll
  for (int nf = 0; nf < 8; ++nf) {
    int c = w * 128 + nf * 16 + m16;
    f32x4 res = *(const f32x4*)&fq[((size_t)b * 512 + c) * 2048 + n0 + q * 4];
    #pragma unroll
    for (int r = 0; r < 4; ++r)
      acc[nf][r] += bmv[nf] + res[r];
  }
  #pragma unroll
  for (int r = 0; r < 4; ++r) {
    float ps = 0.f, pss = 0.f;
    #pragma unroll
    for (int nf = 0; nf < 8; ++nf) {
      float v = acc[nf][r];
      ps += v; pss += v * v;
    }
    ps += __shfl_xor(ps, 1); pss += __shfl_xor(pss, 1);
    ps += __shfl_xor(ps, 2); pss += __shfl_xor(pss, 2);
    ps += __shfl_xor(ps, 4); pss += __shfl_xor(pss, 4);
    ps += __shfl_xor(ps, 8); pss += __shfl_xor(pss, 8);
    if (m16 == 0) {
      ssum[w][q * 4 + r] = ps;
      ssq[w][q * 4 + r] = pss;
    }
  }
  __syncthreads();
  #pragma unroll
  for (int r = 0; r < 4; ++r) {
    int nl = q * 4 + r;
    float S  = ssum[0][nl] + ssum[1][nl] + ssum[2][nl] + ssum[3][nl];
    float SS = ssq[0][nl] + ssq[1][nl] + ssq[2][nl] + ssq[3][nl];
    float mu = S * (1.f / 512.f);
    float var = SS * (1.f / 512.f) - mu * mu;
    float rstd = rsqrtf(var + 1e-5f);
    #pragma unroll
    for (int nf = 0; nf < 8; ++nf)
      acc[nf][r] = (acc[nf][r] - mu) * rstd * gv[nf] + bev[nf];
  }
  #pragma unroll
  for (int nf = 0; nf < 8; ++nf) {
    int c = w * 128 + nf * 16 + m16;
    *(f32x4*)&out[((size_t)b * 512 + c) * 2048 + n0 + q * 4] = acc[nf];
  }
}

// ---------------- launcher ----------------
extern "C" void kernel_launch(void* const* d_in, const int* in_sizes, int n_in,
                              void* d_out, int out_size, void* d_ws, size_t ws_size,
                              hipStream_t stream) {
  const float* fq  = (const float*)d_in[0];
  const float* fk  = (const float*)d_in[1];
  const int*   msk = (const int*)d_in[2];
  const float* Wq  = (const float*)d_in[3];
  const float* bq  = (const float*)d_in[4];
  const float* Wk  = (const float*)d_in[5];
  const float* bk  = (const float*)d_in[6];
  const float* Wf  = (const float*)d_in[7];
  const float* bfv = (const float*)d_in[8];
  const float* Wm  = (const float*)d_in[9];
  const float* bm  = (const float*)d_in[10];
  const float* lng = (const float*)d_in[11];
  const float* lnb = (const float*)d_in[12];
  float* out = (float*)d_out;

  char* ws = (char*)d_ws;
  const size_t MB = 1024 * 1024;
  unsigned short* xqt = (unsigned short*)(ws + 0 * MB);        // 4 MB  [b][n][512] bf16
  unsigned short* xkt = (unsigned short*)(ws + 4 * MB);        // 4 MB
  unsigned short* wqb = (unsigned short*)(ws + 8 * MB);        // 512 KB
  unsigned short* wkb = (unsigned short*)(ws + 8 * MB + 512 * 1024);
  unsigned short* wfb = (unsigned short*)(ws + 9 * MB);
  unsigned short* wmb = (unsigned short*)(ws + 9 * MB + 512 * 1024);
  unsigned short* Qb  = (unsigned short*)(ws + 10 * MB);       // 4 MB  [bh][n][64]
  unsigned short* Kb  = (unsigned short*)(ws + 14 * MB);       // 4 MB  [bh][m][64]
  unsigned short* VTb = (unsigned short*)(ws + 18 * MB);       // 4 MB  [bh][64][m]
  unsigned short* OTb = (unsigned short*)(ws + 22 * MB);       // 4 MB  [b][n][512]
  float*          biasf = (float*)(ws + 26 * MB);              // 16 KB

  hipLaunchKernelGGL(k_pre, dim3(3088), dim3(256), 0, stream,
                     fq, fk, Wq, Wk, Wf, Wm, msk, xqt, xkt, wqb, wkb, wfb, wmb, biasf);
  hipLaunchKernelGGL(k_proj, dim3(768), dim3(256), 0, stream,
                     xqt, xkt, wqb, wkb, wfb, bq, bk, bfv, Qb, Kb, VTb);
  hipLaunchKernelGGL(k_attn2, dim3(512), dim3(256), 0, stream, Qb, Kb, VTb, biasf, OTb);
  hipLaunchKernelGGL(k_out, dim3(128, 2), dim3(256), 0, stream,
                     OTb, wmb, bm, fq, lng, lnb, out);
}